// Round 1
// baseline (604.772 us; speedup 1.0000x reference)
//
#include <hip/hip_runtime.h>
#include <hip/hip_bf16.h>
#include <stdint.h>

typedef unsigned int uint32;
typedef unsigned short u16;
typedef __attribute__((ext_vector_type(4))) float f32x4;
typedef __attribute__((ext_vector_type(8))) __bf16 bf16x8;
typedef __attribute__((ext_vector_type(8))) short i16x8;
typedef __attribute__((ext_vector_type(4))) short i16x4;

#define DEVINL static __device__ __forceinline__

DEVINL u16 f2bf(float f){
  uint32 u = __builtin_bit_cast(uint32, f);
  return (u16)((u + 0x7fffu + ((u >> 16) & 1u)) >> 16);  // RNE
}

DEVINL f32x4 mfma16(bf16x8 a, bf16x8 b, f32x4 c){
  return __builtin_amdgcn_mfma_f32_16x16x32_bf16(a, b, c, 0, 0, 0);
}

static constexpr int LDK = 40;              // padded LDS K-stride (bf16 elems)
static constexpr size_t ISTR = 2048 * 64;   // elems per attention instance
// groups: g = 2048<<grp, r = 1<<grp, offset = grp, nseg = 4>>grp
// inst = base[grp] + ((b*nseg + seg)<<2) + hg ; base = {0,32,48}; 56 total

// ---------------- weight f32 -> bf16 ----------------
__global__ void cvt_w(const float* __restrict__ src, u16* __restrict__ dst, int n4){
  int i = blockIdx.x * 256 + threadIdx.x;
  if (i < n4){
    f32x4 v = *(const f32x4*)(src + (size_t)i * 4);
    u16 o[4];
    #pragma unroll
    for (int j = 0; j < 4; ++j) o[j] = f2bf(v[j]);
    *(i16x4*)(dst + (size_t)i * 4) = *(const i16x4*)o;
  }
}

// ---------------- QKV projection GEMM, scatter-to-gathered epilogue ----------------
// Y[n,e] = X[n,:] . W[e,:] + bias[e]; write bf16 into Yg[inst][t][d]
__global__ __launch_bounds__(256) void qkv_gemm(
    const float* __restrict__ X, const u16* __restrict__ W,
    const float* __restrict__ bias, u16* __restrict__ Yg)
{
  __shared__ u16 As[128 * LDK];
  __shared__ u16 Bs[128 * LDK];
  const int tid = threadIdx.x;
  const int l = tid & 63, w = tid >> 6;
  const int l15 = l & 15, lh = l >> 4;
  const int wr = w >> 1, wc = w & 1;
  const int row0 = blockIdx.x * 128, col0 = blockIdx.y * 128;
  const int sr = tid >> 1, skc = (tid & 1) * 16;

  const float* ap = X + (size_t)(row0 + sr) * 768 + skc;
  const u16*   bp = W + (size_t)(col0 + sr) * 768 + skc;

  f32x4 acc[4][4];
  #pragma unroll
  for (int i = 0; i < 4; ++i)
    #pragma unroll
    for (int j = 0; j < 4; ++j) acc[i][j] = f32x4{0.f, 0.f, 0.f, 0.f};

  f32x4 ra0, ra1, ra2, ra3; i16x8 rb0, rb1;
  ra0 = *(const f32x4*)(ap);      ra1 = *(const f32x4*)(ap + 4);
  ra2 = *(const f32x4*)(ap + 8);  ra3 = *(const f32x4*)(ap + 12);
  rb0 = *(const i16x8*)(bp);      rb1 = *(const i16x8*)(bp + 8);

  for (int ks = 0; ks < 24; ++ks) {
    __syncthreads();
    u16 tmp[16];
    #pragma unroll
    for (int i = 0; i < 4; ++i){
      tmp[i]      = f2bf(ra0[i]); tmp[4 + i]  = f2bf(ra1[i]);
      tmp[8 + i]  = f2bf(ra2[i]); tmp[12 + i] = f2bf(ra3[i]);
    }
    *(i16x8*)&As[sr * LDK + skc]     = *(const i16x8*)tmp;
    *(i16x8*)&As[sr * LDK + skc + 8] = *((const i16x8*)tmp + 1);
    *(i16x8*)&Bs[sr * LDK + skc]     = rb0;
    *(i16x8*)&Bs[sr * LDK + skc + 8] = rb1;
    __syncthreads();
    if (ks < 23) {
      const float* ap2 = ap + (ks + 1) * 32;
      const u16*   bp2 = bp + (ks + 1) * 32;
      ra0 = *(const f32x4*)(ap2);      ra1 = *(const f32x4*)(ap2 + 4);
      ra2 = *(const f32x4*)(ap2 + 8);  ra3 = *(const f32x4*)(ap2 + 12);
      rb0 = *(const i16x8*)(bp2);      rb1 = *(const i16x8*)(bp2 + 8);
    }
    bf16x8 af[4], bfr[4];
    #pragma unroll
    for (int mi = 0; mi < 4; ++mi)
      af[mi] = *(const bf16x8*)&As[(wr * 64 + mi * 16 + l15) * LDK + lh * 8];
    #pragma unroll
    for (int ni = 0; ni < 4; ++ni)
      bfr[ni] = *(const bf16x8*)&Bs[(wc * 64 + ni * 16 + l15) * LDK + lh * 8];
    #pragma unroll
    for (int mi = 0; mi < 4; ++mi)
      #pragma unroll
      for (int ni = 0; ni < 4; ++ni)
        acc[mi][ni] = mfma16(af[mi], bfr[ni], acc[mi][ni]);
  }

  // scatter epilogue: C layout col=lane&15, row=(lane>>4)*4+reg  [m89]
  #pragma unroll
  for (int ni = 0; ni < 4; ++ni) {
    const int e = col0 + wc * 64 + ni * 16 + l15;
    const int h = e >> 6, d = e & 63;
    const int grp = h >> 2, hg = h & 3;
    const int instB = (grp == 0) ? 0 : (grp == 1) ? 32 : 48;
    const float bia = bias[e];
    #pragma unroll
    for (int mi = 0; mi < 4; ++mi) {
      #pragma unroll
      for (int r = 0; r < 4; ++r) {
        const int row = row0 + wr * 64 + mi * 16 + lh * 4 + r;
        const int b = row >> 13, nn = row & 8191;
        const int p = nn & ((2048 << grp) - 1);
        if ((p & ((1 << grp) - 1)) != grp) continue;   // off dilation grid
        const int seg = nn >> (11 + grp);
        const int t = (p - grp) >> grp;
        const int inst = instB + ((b * (4 >> grp) + seg) << 2) + hg;
        Yg[(size_t)inst * ISTR + (size_t)t * 64 + d] = f2bf(acc[mi][ni][r] + bia);
      }
    }
  }
}

// ---------------- V transpose: Vg[inst][t][d] -> VgT[inst][d][t] ----------------
__global__ __launch_bounds__(256) void v_transpose(
    const u16* __restrict__ Vg, u16* __restrict__ VgT)
{
  __shared__ u16 tile[64 * 72];
  const size_t ibase = (size_t)blockIdx.y * ISTR;
  const int tb = blockIdx.x;                // 32 tiles of 64 t-rows
  const int tid = threadIdx.x;
  const int r = tid >> 2, c4 = (tid & 3) * 16;
  const u16* src = Vg + ibase + (size_t)(tb * 64 + r) * 64 + c4;
  *(i16x8*)&tile[r * 72 + c4]     = *(const i16x8*)src;
  *(i16x8*)&tile[r * 72 + c4 + 8] = *(const i16x8*)(src + 8);
  __syncthreads();
  u16 o[16];
  #pragma unroll
  for (int j = 0; j < 16; ++j) o[j] = tile[(c4 + j) * 72 + r];
  u16* dst = VgT + ibase + (size_t)r * 2048 + tb * 64 + c4;
  *(i16x8*)dst       = *(const i16x8*)o;
  *(i16x8*)(dst + 8) = *((const i16x8*)o + 1);
}

// ---------------- dilated flash attention ----------------
// one block = 4 independent waves; wave = 16 q rows; loop kk tiles of 32
__global__ __launch_bounds__(256) void dil_attn(
    const u16* __restrict__ Qg, const u16* __restrict__ Kg,
    const u16* __restrict__ VgT, float* __restrict__ Og)
{
  __shared__ u16 P[4 * 16 * 40];
  const int tid = threadIdx.x;
  const int l = tid & 63, w = tid >> 6;
  const int l15 = l & 15, lh = l >> 4;
  const size_t ibase = (size_t)blockIdx.y * ISTR;
  const int qbase = blockIdx.x * 64 + w * 16;

  const u16* qp = Qg + ibase + (size_t)(qbase + l15) * 64 + lh * 8;
  const bf16x8 aq0 = *(const bf16x8*)qp;
  const bf16x8 aq1 = *(const bf16x8*)(qp + 32);

  f32x4 o0 = {0.f,0.f,0.f,0.f}, o1 = o0, o2 = o0, o3 = o0;
  float m[4]  = {-1e30f, -1e30f, -1e30f, -1e30f};
  float ls[4] = {0.f, 0.f, 0.f, 0.f};
  u16* myP = &P[w * 16 * 40];
  const float L2E = 1.4426950408889634f;

  const u16* kbase = Kg + ibase + (size_t)l15 * 64 + lh * 8;
  const u16* vbase = VgT + ibase + (size_t)l15 * 2048 + lh * 8;

  for (int kk0 = 0; kk0 < 2048; kk0 += 32) {
    const u16* kp = kbase + (size_t)kk0 * 64;
    bf16x8 kA0 = *(const bf16x8*)kp;
    bf16x8 kA1 = *(const bf16x8*)(kp + 32);
    bf16x8 kB0 = *(const bf16x8*)(kp + 1024);
    bf16x8 kB1 = *(const bf16x8*)(kp + 1024 + 32);
    f32x4 z = {0.f,0.f,0.f,0.f};
    f32x4 sA = mfma16(aq0, kA0, z); sA = mfma16(aq1, kA1, sA);
    f32x4 sB = mfma16(aq0, kB0, z); sB = mfma16(aq1, kB1, sB);

    float pA[4], pB[4], cm[4], rsum[4], fr[4];
    #pragma unroll
    for (int r = 0; r < 4; ++r) {
      sA[r] *= 0.125f; sB[r] *= 0.125f;
      cm[r] = fmaxf(sA[r], sB[r]);
    }
    #pragma unroll
    for (int off = 1; off < 16; off <<= 1)
      #pragma unroll
      for (int r = 0; r < 4; ++r) cm[r] = fmaxf(cm[r], __shfl_xor(cm[r], off));
    #pragma unroll
    for (int r = 0; r < 4; ++r) {
      const float mn = fmaxf(m[r], cm[r]);
      fr[r] = exp2f((m[r] - mn) * L2E);
      m[r] = mn;
      pA[r] = exp2f((sA[r] - mn) * L2E);
      pB[r] = exp2f((sB[r] - mn) * L2E);
      rsum[r] = pA[r] + pB[r];
    }
    #pragma unroll
    for (int off = 1; off < 16; off <<= 1)
      #pragma unroll
      for (int r = 0; r < 4; ++r) rsum[r] += __shfl_xor(rsum[r], off);
    #pragma unroll
    for (int r = 0; r < 4; ++r) {
      ls[r] = ls[r] * fr[r] + rsum[r];
      o0[r] *= fr[r]; o1[r] *= fr[r]; o2[r] *= fr[r]; o3[r] *= fr[r];
      myP[(lh * 4 + r) * 40 + l15]      = f2bf(pA[r]);
      myP[(lh * 4 + r) * 40 + 16 + l15] = f2bf(pB[r]);
    }
    __builtin_amdgcn_wave_barrier();           // in-wave LDS transpose: DS pipe is in-order per wave
    const bf16x8 pf = *(const bf16x8*)&myP[l15 * 40 + lh * 8];
    __builtin_amdgcn_wave_barrier();
    const u16* vp = vbase + kk0;
    bf16x8 v0 = *(const bf16x8*)vp;
    bf16x8 v1 = *(const bf16x8*)(vp + 16 * 2048);
    bf16x8 v2 = *(const bf16x8*)(vp + 32 * 2048);
    bf16x8 v3 = *(const bf16x8*)(vp + 48 * 2048);
    o0 = mfma16(pf, v0, o0);
    o1 = mfma16(pf, v1, o1);
    o2 = mfma16(pf, v2, o2);
    o3 = mfma16(pf, v3, o3);
  }

  #pragma unroll
  for (int r = 0; r < 4; ++r) {
    const float inv = 1.0f / (3.0f * ls[r]);   // fold /G here
    float* op = Og + ibase + (size_t)(qbase + lh * 4 + r) * 64 + l15;
    op[0]  = o0[r] * inv;
    op[16] = o1[r] * inv;
    op[32] = o2[r] * inv;
    op[48] = o3[r] * inv;
  }
}

// ---------------- gather + LayerNorm -> xln (bf16) ----------------
__global__ __launch_bounds__(256) void ln_gather(
    const float* __restrict__ Og, const float* __restrict__ gamma,
    const float* __restrict__ beta, u16* __restrict__ xln)
{
  const int row = blockIdx.x;            // 0..16383
  const int b = row >> 13, nn = row & 8191;
  const int tid = threadIdx.x;
  float v[3];
  #pragma unroll
  for (int j = 0; j < 3; ++j) {
    const int e = tid + j * 256;
    const int h = e >> 6, d = e & 63;
    const int grp = h >> 2, hg = h & 3;
    const int p = nn & ((2048 << grp) - 1);
    float val = 0.f;
    if ((p & ((1 << grp) - 1)) == grp) {
      const int seg = nn >> (11 + grp);
      const int instB = (grp == 0) ? 0 : (grp == 1) ? 32 : 48;
      const int inst = instB + ((b * (4 >> grp) + seg) << 2) + hg;
      const int t = (p - grp) >> grp;
      val = Og[(size_t)inst * ISTR + (size_t)t * 64 + d];
    }
    v[j] = val;
  }
  float s = v[0] + v[1] + v[2];
  float q = v[0]*v[0] + v[1]*v[1] + v[2]*v[2];
  #pragma unroll
  for (int off = 1; off < 64; off <<= 1) { s += __shfl_xor(s, off); q += __shfl_xor(q, off); }
  __shared__ float red[8];
  const int w = tid >> 6, l = tid & 63;
  if (l == 0) { red[w] = s; red[4 + w] = q; }
  __syncthreads();
  s = red[0] + red[1] + red[2] + red[3];
  q = red[4] + red[5] + red[6] + red[7];
  const float mu = s * (1.f / 768.f);
  const float var = q * (1.f / 768.f) - mu * mu;
  const float rs = rsqrtf(var + 1e-5f);
  #pragma unroll
  for (int j = 0; j < 3; ++j) {
    const int e = tid + j * 256;
    xln[(size_t)row * 768 + e] = f2bf((v[j] - mu) * rs * gamma[e] + beta[e]);
  }
}

// ---------------- output projection GEMM (bf16 A, f32 out) ----------------
__global__ __launch_bounds__(256) void out_gemm(
    const u16* __restrict__ Xb, const u16* __restrict__ W,
    const float* __restrict__ bias, float* __restrict__ out)
{
  __shared__ u16 As[128 * LDK];
  __shared__ u16 Bs[128 * LDK];
  const int tid = threadIdx.x;
  const int l = tid & 63, w = tid >> 6;
  const int l15 = l & 15, lh = l >> 4;
  const int wr = w >> 1, wc = w & 1;
  const int row0 = blockIdx.x * 128, col0 = blockIdx.y * 128;
  const int sr = tid >> 1, skc = (tid & 1) * 16;

  const u16* ap = Xb + (size_t)(row0 + sr) * 768 + skc;
  const u16* bp = W + (size_t)(col0 + sr) * 768 + skc;

  f32x4 acc[4][4];
  #pragma unroll
  for (int i = 0; i < 4; ++i)
    #pragma unroll
    for (int j = 0; j < 4; ++j) acc[i][j] = f32x4{0.f, 0.f, 0.f, 0.f};

  i16x8 ra0, ra1, rb0, rb1;
  ra0 = *(const i16x8*)(ap); ra1 = *(const i16x8*)(ap + 8);
  rb0 = *(const i16x8*)(bp); rb1 = *(const i16x8*)(bp + 8);

  for (int ks = 0; ks < 24; ++ks) {
    __syncthreads();
    *(i16x8*)&As[sr * LDK + skc]     = ra0;
    *(i16x8*)&As[sr * LDK + skc + 8] = ra1;
    *(i16x8*)&Bs[sr * LDK + skc]     = rb0;
    *(i16x8*)&Bs[sr * LDK + skc + 8] = rb1;
    __syncthreads();
    if (ks < 23) {
      const u16* ap2 = ap + (ks + 1) * 32;
      const u16* bp2 = bp + (ks + 1) * 32;
      ra0 = *(const i16x8*)(ap2); ra1 = *(const i16x8*)(ap2 + 8);
      rb0 = *(const i16x8*)(bp2); rb1 = *(const i16x8*)(bp2 + 8);
    }
    bf16x8 af[4], bfr[4];
    #pragma unroll
    for (int mi = 0; mi < 4; ++mi)
      af[mi] = *(const bf16x8*)&As[(wr * 64 + mi * 16 + l15) * LDK + lh * 8];
    #pragma unroll
    for (int ni = 0; ni < 4; ++ni)
      bfr[ni] = *(const bf16x8*)&Bs[(wc * 64 + ni * 16 + l15) * LDK + lh * 8];
    #pragma unroll
    for (int mi = 0; mi < 4; ++mi)
      #pragma unroll
      for (int ni = 0; ni < 4; ++ni)
        acc[mi][ni] = mfma16(af[mi], bfr[ni], acc[mi][ni]);
  }

  #pragma unroll
  for (int ni = 0; ni < 4; ++ni) {
    const int e = col0 + wc * 64 + ni * 16 + l15;
    const float bia = bias[e];
    #pragma unroll
    for (int mi = 0; mi < 4; ++mi) {
      #pragma unroll
      for (int r = 0; r < 4; ++r) {
        const int row = row0 + wr * 64 + mi * 16 + lh * 4 + r;
        out[(size_t)row * 768 + e] = acc[mi][ni][r] + bia;
      }
    }
  }
}

extern "C" void kernel_launch(void* const* d_in, const int* in_sizes, int n_in,
                              void* d_out, int out_size, void* d_ws, size_t ws_size,
                              hipStream_t stream) {
  const float* query = (const float*)d_in[0];
  const float* key_  = (const float*)d_in[1];
  const float* value = (const float*)d_in[2];
  const float* Wq = (const float*)d_in[3];
  const float* bq = (const float*)d_in[4];
  const float* Wk = (const float*)d_in[5];
  const float* bk = (const float*)d_in[6];
  const float* Wv = (const float*)d_in[7];
  const float* bv = (const float*)d_in[8];
  const float* Wo = (const float*)d_in[9];
  const float* bo = (const float*)d_in[10];
  const float* lng = (const float*)d_in[11];
  const float* lnb = (const float*)d_in[12];

  char* ws = (char*)d_ws;
  size_t off = 0;
  auto alloc = [&](size_t bytes) { size_t o = off; off += (bytes + 255) & ~(size_t)255; return o; };
  const size_t WB = 768 * 768 * 2;           // bf16 weight bytes
  const size_t GB = (size_t)56 * ISTR * 2;   // gathered bf16 bytes
  u16* wqb = (u16*)(ws + alloc(WB));
  u16* wkb = (u16*)(ws + alloc(WB));
  u16* wvb = (u16*)(ws + alloc(WB));
  u16* wob = (u16*)(ws + alloc(WB));
  u16* Qg  = (u16*)(ws + alloc(GB));
  u16* Kg  = (u16*)(ws + alloc(GB));
  u16* Vg  = (u16*)(ws + alloc(GB));
  u16* VgT = (u16*)(ws + alloc(GB));
  float* Og = (float*)(ws + alloc((size_t)56 * ISTR * 4));
  u16* xln = (u16*)(ws + alloc((size_t)16384 * 768 * 2));

  const int n4 = 768 * 768 / 4;
  cvt_w<<<dim3(576), 256, 0, stream>>>(Wq, wqb, n4);
  cvt_w<<<dim3(576), 256, 0, stream>>>(Wk, wkb, n4);
  cvt_w<<<dim3(576), 256, 0, stream>>>(Wv, wvb, n4);
  cvt_w<<<dim3(576), 256, 0, stream>>>(Wo, wob, n4);

  qkv_gemm<<<dim3(128, 6), 256, 0, stream>>>(query, wqb, bq, Qg);
  qkv_gemm<<<dim3(128, 6), 256, 0, stream>>>(key_,  wkb, bk, Kg);
  qkv_gemm<<<dim3(128, 6), 256, 0, stream>>>(value, wvb, bv, Vg);

  v_transpose<<<dim3(32, 56), 256, 0, stream>>>(Vg, VgT);
  dil_attn<<<dim3(32, 56), 256, 0, stream>>>(Qg, Kg, VgT, Og);
  ln_gather<<<dim3(16384), 256, 0, stream>>>(Og, lng, lnb, xln);
  out_gemm<<<dim3(128, 6), 256, 0, stream>>>(xln, wob, bo, (float*)d_out);
}

// Round 2
// 443.315 us; speedup vs baseline: 1.3642x; 1.3642x over previous
//
#include <hip/hip_runtime.h>
#include <hip/hip_bf16.h>
#include <stdint.h>

typedef unsigned int uint32;
typedef unsigned short u16;
typedef __attribute__((ext_vector_type(4))) float f32x4;
typedef __attribute__((ext_vector_type(16))) float f32x16;
typedef __attribute__((ext_vector_type(8))) __bf16 bf16x8;
typedef __attribute__((ext_vector_type(8))) short i16x8;
typedef __attribute__((ext_vector_type(4))) short i16x4;
typedef __attribute__((ext_vector_type(4))) uint32 u32x4;

#define DEVINL static __device__ __forceinline__

DEVINL u16 f2bf(float f){
  uint32 u = __builtin_bit_cast(uint32, f);
  return (u16)((u + 0x7fffu + ((u >> 16) & 1u)) >> 16);  // RNE
}

DEVINL uint32 cvtpk(float lo, float hi){
  uint32 r;
  asm("v_cvt_pk_bf16_f32 %0, %1, %2" : "=v"(r) : "v"(lo), "v"(hi));
  return r;
}

// vdst.hi32lanes <-> vsrc.lo32lanes  (CDNA4: DST.row1 <-> SRC.row0)
DEVINL void permswap(uint32 &a, uint32 &b){
  asm volatile("s_nop 1\n\tv_permlane32_swap_b32 %0, %1" : "+v"(a), "+v"(b));
}

DEVINL f32x4 mfma16(bf16x8 a, bf16x8 b, f32x4 c){
  return __builtin_amdgcn_mfma_f32_16x16x32_bf16(a, b, c, 0, 0, 0);
}
DEVINL f32x16 mfma32(bf16x8 a, bf16x8 b, f32x16 c){
  return __builtin_amdgcn_mfma_f32_32x32x16_bf16(a, b, c, 0, 0, 0);
}
DEVINL f32x16 zero16(){
  f32x16 z;
  #pragma unroll
  for (int r = 0; r < 16; ++r) z[r] = 0.f;
  return z;
}

static constexpr int LDK = 40;              // padded LDS K-stride (bf16 elems)
static constexpr size_t ISTR = 2048 * 64;   // elems per attention instance
static constexpr float QSCALE = 0.18033688011112042f;  // log2(e)/8 folded into Q

// ---------------- weight f32 -> bf16 ----------------
__global__ void cvt_w(const float* __restrict__ src, u16* __restrict__ dst, int n4){
  int i = blockIdx.x * 256 + threadIdx.x;
  if (i < n4){
    f32x4 v = *(const f32x4*)(src + (size_t)i * 4);
    u16 o[4];
    #pragma unroll
    for (int j = 0; j < 4; ++j) o[j] = f2bf(v[j]);
    *(i16x4*)(dst + (size_t)i * 4) = *(const i16x4*)o;
  }
}

// ---------------- QKV projection GEMM, scatter-to-gathered epilogue ----------------
// Y[n,e] = (X[n,:].W[e,:] + bias[e]) * scale ; write bf16 into
//   tmode==0: Yg[inst][t][d]      tmode==1: Yg[inst][d][t]  (direct V^T)
__global__ __launch_bounds__(256) void qkv_gemm(
    const float* __restrict__ X, const u16* __restrict__ W,
    const float* __restrict__ bias, u16* __restrict__ Yg,
    float scale, int tmode)
{
  __shared__ u16 As[128 * LDK];
  __shared__ u16 Bs[128 * LDK];
  const int tid = threadIdx.x;
  const int l = tid & 63, w = tid >> 6;
  const int l15 = l & 15, lh = l >> 4;
  const int wr = w >> 1, wc = w & 1;
  const int row0 = blockIdx.x * 128, col0 = blockIdx.y * 128;
  const int sr = tid >> 1, skc = (tid & 1) * 16;

  const float* ap = X + (size_t)(row0 + sr) * 768 + skc;
  const u16*   bp = W + (size_t)(col0 + sr) * 768 + skc;

  f32x4 acc[4][4];
  #pragma unroll
  for (int i = 0; i < 4; ++i)
    #pragma unroll
    for (int j = 0; j < 4; ++j) acc[i][j] = f32x4{0.f, 0.f, 0.f, 0.f};

  f32x4 ra0, ra1, ra2, ra3; i16x8 rb0, rb1;
  ra0 = *(const f32x4*)(ap);      ra1 = *(const f32x4*)(ap + 4);
  ra2 = *(const f32x4*)(ap + 8);  ra3 = *(const f32x4*)(ap + 12);
  rb0 = *(const i16x8*)(bp);      rb1 = *(const i16x8*)(bp + 8);

  for (int ks = 0; ks < 24; ++ks) {
    __syncthreads();
    u32x4 w0 = { cvtpk(ra0[0], ra0[1]), cvtpk(ra0[2], ra0[3]),
                 cvtpk(ra1[0], ra1[1]), cvtpk(ra1[2], ra1[3]) };
    u32x4 w1 = { cvtpk(ra2[0], ra2[1]), cvtpk(ra2[2], ra2[3]),
                 cvtpk(ra3[0], ra3[1]), cvtpk(ra3[2], ra3[3]) };
    *(i16x8*)&As[sr * LDK + skc]     = __builtin_bit_cast(i16x8, w0);
    *(i16x8*)&As[sr * LDK + skc + 8] = __builtin_bit_cast(i16x8, w1);
    *(i16x8*)&Bs[sr * LDK + skc]     = rb0;
    *(i16x8*)&Bs[sr * LDK + skc + 8] = rb1;
    __syncthreads();
    if (ks < 23) {
      const float* ap2 = ap + (ks + 1) * 32;
      const u16*   bp2 = bp + (ks + 1) * 32;
      ra0 = *(const f32x4*)(ap2);      ra1 = *(const f32x4*)(ap2 + 4);
      ra2 = *(const f32x4*)(ap2 + 8);  ra3 = *(const f32x4*)(ap2 + 12);
      rb0 = *(const i16x8*)(bp2);      rb1 = *(const i16x8*)(bp2 + 8);
    }
    bf16x8 af[4], bfr[4];
    #pragma unroll
    for (int mi = 0; mi < 4; ++mi)
      af[mi] = *(const bf16x8*)&As[(wr * 64 + mi * 16 + l15) * LDK + lh * 8];
    #pragma unroll
    for (int ni = 0; ni < 4; ++ni)
      bfr[ni] = *(const bf16x8*)&Bs[(wc * 64 + ni * 16 + l15) * LDK + lh * 8];
    #pragma unroll
    for (int mi = 0; mi < 4; ++mi)
      #pragma unroll
      for (int ni = 0; ni < 4; ++ni)
        acc[mi][ni] = mfma16(af[mi], bfr[ni], acc[mi][ni]);
  }

  // scatter epilogue: C layout col=lane&15, row=(lane>>4)*4+reg  [m89]
  #pragma unroll
  for (int ni = 0; ni < 4; ++ni) {
    const int e = col0 + wc * 64 + ni * 16 + l15;
    const int h = e >> 6, d = e & 63;
    const int grp = h >> 2, hg = h & 3;
    const int instB = (grp == 0) ? 0 : (grp == 1) ? 32 : 48;
    const float bia = bias[e];
    #pragma unroll
    for (int mi = 0; mi < 4; ++mi) {
      #pragma unroll
      for (int r = 0; r < 4; ++r) {
        const int row = row0 + wr * 64 + mi * 16 + lh * 4 + r;
        const int b = row >> 13, nn = row & 8191;
        const int p = nn & ((2048 << grp) - 1);
        if ((p & ((1 << grp) - 1)) != grp) continue;   // off dilation grid
        const int seg = nn >> (11 + grp);
        const int t = (p - grp) >> grp;
        const int inst = instB + ((b * (4 >> grp) + seg) << 2) + hg;
        const u16 val = f2bf((acc[mi][ni][r] + bia) * scale);
        if (tmode == 0) Yg[(size_t)inst * ISTR + (size_t)t * 64 + d] = val;
        else            Yg[(size_t)inst * ISTR + (size_t)d * 2048 + t] = val;
      }
    }
  }
}

// ---------------- dilated flash attention (32x32 MFMA, swapped QK^T) ----------------
// block = 4 waves, wave = 32 q rows; no-max softmax; normalization deferred to ln_gather
__global__ __launch_bounds__(256) void dil_attn(
    const u16* __restrict__ Qg, const u16* __restrict__ Kg,
    const u16* __restrict__ VgT, float* __restrict__ Og, float* __restrict__ Ls)
{
  const int tid = threadIdx.x;
  const int l = tid & 63, w = tid >> 6;
  const int l31 = l & 31, hi = l >> 5;
  // XCD-bijective swizzle: 896 blocks = 8 XCD x 112; one instance (16 blocks) per XCD
  const int id = blockIdx.x + (blockIdx.y << 4);
  const int nid = (id & 7) * 112 + (id >> 3);
  const int inst = nid >> 4, qt = nid & 15;
  const size_t ibase = (size_t)inst * ISTR;
  const int qbase = qt * 128 + w * 32;

  // Q as B-frag (already scaled by log2(e)/8): lane holds Q[q=l31][d=m*16+hi*8+j]
  const u16* qlane = Qg + ibase + (size_t)(qbase + l31) * 64 + hi * 8;
  bf16x8 qf0 = *(const bf16x8*)(qlane);
  bf16x8 qf1 = *(const bf16x8*)(qlane + 16);
  bf16x8 qf2 = *(const bf16x8*)(qlane + 32);
  bf16x8 qf3 = *(const bf16x8*)(qlane + 48);

  const u16* klane  = Kg  + ibase + (size_t)l31 * 64 + hi * 8;
  const u16* vlane0 = VgT + ibase + (size_t)l31 * 2048 + hi * 8;
  const u16* vlane1 = vlane0 + (size_t)32 * 2048;

  f32x16 acc0 = zero16(), acc1 = zero16(), rsacc = zero16();

  // K as A-frag: lane holds K[k=kk0+l31][d=m*16+hi*8+j]
  bf16x8 kc0 = *(const bf16x8*)(klane);
  bf16x8 kc1 = *(const bf16x8*)(klane + 16);
  bf16x8 kc2 = *(const bf16x8*)(klane + 32);
  bf16x8 kc3 = *(const bf16x8*)(klane + 48);

  for (int kk0 = 0; kk0 < 2048; kk0 += 32) {
    // V (current tile) issued early: B-frag V[k=kk0+kh*16+hi*8+j][d=dt*32+l31]
    const u16* vp0 = vlane0 + kk0;
    const u16* vp1 = vlane1 + kk0;
    bf16x8 v00 = *(const bf16x8*)(vp0);
    bf16x8 v01 = *(const bf16x8*)(vp0 + 16);
    bf16x8 v10 = *(const bf16x8*)(vp1);
    bf16x8 v11 = *(const bf16x8*)(vp1 + 16);

    // S^T[k][q] : 4 MFMAs over d
    f32x16 sT = zero16();
    sT = mfma32(kc0, qf0, sT);
    sT = mfma32(kc1, qf1, sT);
    sT = mfma32(kc2, qf2, sT);
    sT = mfma32(kc3, qf3, sT);

    // prefetch next K tile (wraps on last iter; harmless)
    {
      const int nk = (kk0 + 32) & 2047;
      const u16* kp = klane + (size_t)nk * 64;
      kc0 = *(const bf16x8*)(kp);
      kc1 = *(const bf16x8*)(kp + 16);
      kc2 = *(const bf16x8*)(kp + 32);
      kc3 = *(const bf16x8*)(kp + 48);
    }

    // no-max softmax: P = exp2(S^T)  (scale pre-folded into Q)
    float p[16];
    #pragma unroll
    for (int r = 0; r < 16; ++r) p[r] = exp2f(sT[r]);
    #pragma unroll
    for (int r = 0; r < 16; ++r) rsacc[r] += p[r];

    // P (C-layout) -> A-frag via cvt_pk + permlane32_swap  [T12]
    uint32 cw0 = cvtpk(p[0],  p[1]),  cw1 = cvtpk(p[2],  p[3]);
    uint32 cw2 = cvtpk(p[4],  p[5]),  cw3 = cvtpk(p[6],  p[7]);
    uint32 cw4 = cvtpk(p[8],  p[9]),  cw5 = cvtpk(p[10], p[11]);
    uint32 cw6 = cvtpk(p[12], p[13]), cw7 = cvtpk(p[14], p[15]);
    permswap(cw0, cw2); permswap(cw1, cw3);
    permswap(cw4, cw6); permswap(cw5, cw7);
    bf16x8 pa0 = __builtin_bit_cast(bf16x8, u32x4{cw0, cw1, cw2, cw3});  // k 0..15
    bf16x8 pa1 = __builtin_bit_cast(bf16x8, u32x4{cw4, cw5, cw6, cw7});  // k 16..31

    acc0 = mfma32(pa0, v00, acc0);
    acc0 = mfma32(pa1, v01, acc0);
    acc1 = mfma32(pa0, v10, acc1);
    acc1 = mfma32(pa1, v11, acc1);
  }

  // row-sum finalize: lane holds partials for q = l31
  float hs = 0.f;
  #pragma unroll
  for (int r = 0; r < 16; ++r) hs += rsacc[r];
  hs += __shfl_xor(hs, 32);
  const float inv = 1.0f / (3.0f * hs);
  if (l < 32) Ls[(size_t)inst * 2048 + qbase + l] = inv;

  // store O (unnormalized): C row q=(reg&3)+8*(reg>>2)+4*hi, col d
  float* ob = Og + ibase + (size_t)qbase * 64;
  #pragma unroll
  for (int r = 0; r < 16; ++r) {
    const int qrow = (r & 3) + 8 * (r >> 2) + 4 * hi;
    ob[(size_t)qrow * 64 + l31]      = acc0[r];
    ob[(size_t)qrow * 64 + 32 + l31] = acc1[r];
  }
}

// ---------------- gather + normalize + LayerNorm -> xln (bf16) ----------------
__global__ __launch_bounds__(256) void ln_gather(
    const float* __restrict__ Og, const float* __restrict__ Ls,
    const float* __restrict__ gamma, const float* __restrict__ beta,
    u16* __restrict__ xln)
{
  const int row = blockIdx.x;            // 0..16383
  const int b = row >> 13, nn = row & 8191;
  const int tid = threadIdx.x;
  float v[3];
  #pragma unroll
  for (int j = 0; j < 3; ++j) {
    const int e = tid + j * 256;
    const int h = e >> 6, d = e & 63;
    const int grp = h >> 2, hg = h & 3;
    const int p = nn & ((2048 << grp) - 1);
    float val = 0.f;
    if ((p & ((1 << grp) - 1)) == grp) {
      const int seg = nn >> (11 + grp);
      const int instB = (grp == 0) ? 0 : (grp == 1) ? 32 : 48;
      const int inst = instB + ((b * (4 >> grp) + seg) << 2) + hg;
      const int t = (p - grp) >> grp;
      val = Og[(size_t)inst * ISTR + (size_t)t * 64 + d]
          * Ls[(size_t)inst * 2048 + t];
    }
    v[j] = val;
  }
  float s = v[0] + v[1] + v[2];
  float q = v[0]*v[0] + v[1]*v[1] + v[2]*v[2];
  #pragma unroll
  for (int off = 1; off < 64; off <<= 1) { s += __shfl_xor(s, off); q += __shfl_xor(q, off); }
  __shared__ float red[8];
  const int w = tid >> 6, l = tid & 63;
  if (l == 0) { red[w] = s; red[4 + w] = q; }
  __syncthreads();
  s = red[0] + red[1] + red[2] + red[3];
  q = red[4] + red[5] + red[6] + red[7];
  const float mu = s * (1.f / 768.f);
  const float var = q * (1.f / 768.f) - mu * mu;
  const float rs = rsqrtf(var + 1e-5f);
  #pragma unroll
  for (int j = 0; j < 3; ++j) {
    const int e = tid + j * 256;
    xln[(size_t)row * 768 + e] = f2bf((v[j] - mu) * rs * gamma[e] + beta[e]);
  }
}

// ---------------- output projection GEMM (bf16 A, f32 out) ----------------
__global__ __launch_bounds__(256) void out_gemm(
    const u16* __restrict__ Xb, const u16* __restrict__ W,
    const float* __restrict__ bias, float* __restrict__ out)
{
  __shared__ u16 As[128 * LDK];
  __shared__ u16 Bs[128 * LDK];
  const int tid = threadIdx.x;
  const int l = tid & 63, w = tid >> 6;
  const int l15 = l & 15, lh = l >> 4;
  const int wr = w >> 1, wc = w & 1;
  const int row0 = blockIdx.x * 128, col0 = blockIdx.y * 128;
  const int sr = tid >> 1, skc = (tid & 1) * 16;

  const u16* ap = Xb + (size_t)(row0 + sr) * 768 + skc;
  const u16* bp = W + (size_t)(col0 + sr) * 768 + skc;

  f32x4 acc[4][4];
  #pragma unroll
  for (int i = 0; i < 4; ++i)
    #pragma unroll
    for (int j = 0; j < 4; ++j) acc[i][j] = f32x4{0.f, 0.f, 0.f, 0.f};

  i16x8 ra0, ra1, rb0, rb1;
  ra0 = *(const i16x8*)(ap); ra1 = *(const i16x8*)(ap + 8);
  rb0 = *(const i16x8*)(bp); rb1 = *(const i16x8*)(bp + 8);

  for (int ks = 0; ks < 24; ++ks) {
    __syncthreads();
    *(i16x8*)&As[sr * LDK + skc]     = ra0;
    *(i16x8*)&As[sr * LDK + skc + 8] = ra1;
    *(i16x8*)&Bs[sr * LDK + skc]     = rb0;
    *(i16x8*)&Bs[sr * LDK + skc + 8] = rb1;
    __syncthreads();
    if (ks < 23) {
      const u16* ap2 = ap + (ks + 1) * 32;
      const u16* bp2 = bp + (ks + 1) * 32;
      ra0 = *(const i16x8*)(ap2); ra1 = *(const i16x8*)(ap2 + 8);
      rb0 = *(const i16x8*)(bp2); rb1 = *(const i16x8*)(bp2 + 8);
    }
    bf16x8 af[4], bfr[4];
    #pragma unroll
    for (int mi = 0; mi < 4; ++mi)
      af[mi] = *(const bf16x8*)&As[(wr * 64 + mi * 16 + l15) * LDK + lh * 8];
    #pragma unroll
    for (int ni = 0; ni < 4; ++ni)
      bfr[ni] = *(const bf16x8*)&Bs[(wc * 64 + ni * 16 + l15) * LDK + lh * 8];
    #pragma unroll
    for (int mi = 0; mi < 4; ++mi)
      #pragma unroll
      for (int ni = 0; ni < 4; ++ni)
        acc[mi][ni] = mfma16(af[mi], bfr[ni], acc[mi][ni]);
  }

  #pragma unroll
  for (int ni = 0; ni < 4; ++ni) {
    const int e = col0 + wc * 64 + ni * 16 + l15;
    const float bia = bias[e];
    #pragma unroll
    for (int mi = 0; mi < 4; ++mi) {
      #pragma unroll
      for (int r = 0; r < 4; ++r) {
        const int row = row0 + wr * 64 + mi * 16 + lh * 4 + r;
        out[(size_t)row * 768 + e] = acc[mi][ni][r] + bia;
      }
    }
  }
}

extern "C" void kernel_launch(void* const* d_in, const int* in_sizes, int n_in,
                              void* d_out, int out_size, void* d_ws, size_t ws_size,
                              hipStream_t stream) {
  const float* query = (const float*)d_in[0];
  const float* key_  = (const float*)d_in[1];
  const float* value = (const float*)d_in[2];
  const float* Wq = (const float*)d_in[3];
  const float* bq = (const float*)d_in[4];
  const float* Wk = (const float*)d_in[5];
  const float* bk = (const float*)d_in[6];
  const float* Wv = (const float*)d_in[7];
  const float* bv = (const float*)d_in[8];
  const float* Wo = (const float*)d_in[9];
  const float* bo = (const float*)d_in[10];
  const float* lng = (const float*)d_in[11];
  const float* lnb = (const float*)d_in[12];

  char* ws = (char*)d_ws;
  size_t off = 0;
  auto alloc = [&](size_t bytes) { size_t o = off; off += (bytes + 255) & ~(size_t)255; return o; };
  const size_t WB = 768 * 768 * 2;           // bf16 weight bytes
  const size_t GB = (size_t)56 * ISTR * 2;   // gathered bf16 bytes
  u16* wqb = (u16*)(ws + alloc(WB));
  u16* wkb = (u16*)(ws + alloc(WB));
  u16* wvb = (u16*)(ws + alloc(WB));
  u16* wob = (u16*)(ws + alloc(WB));
  u16* Qg  = (u16*)(ws + alloc(GB));
  u16* Kg  = (u16*)(ws + alloc(GB));
  u16* VgT = (u16*)(ws + alloc(GB));
  float* Og = (float*)(ws + alloc((size_t)56 * ISTR * 4));
  float* Lsb = (float*)(ws + alloc((size_t)56 * 2048 * 4));
  u16* xln = (u16*)(ws + alloc((size_t)16384 * 768 * 2));

  const int n4 = 768 * 768 / 4;
  cvt_w<<<dim3(576), 256, 0, stream>>>(Wq, wqb, n4);
  cvt_w<<<dim3(576), 256, 0, stream>>>(Wk, wkb, n4);
  cvt_w<<<dim3(576), 256, 0, stream>>>(Wv, wvb, n4);
  cvt_w<<<dim3(576), 256, 0, stream>>>(Wo, wob, n4);

  qkv_gemm<<<dim3(128, 6), 256, 0, stream>>>(query, wqb, bq, Qg, QSCALE, 0);
  qkv_gemm<<<dim3(128, 6), 256, 0, stream>>>(key_,  wkb, bk, Kg, 1.0f, 0);
  qkv_gemm<<<dim3(128, 6), 256, 0, stream>>>(value, wvb, bv, VgT, 1.0f, 1);

  dil_attn<<<dim3(16, 56), 256, 0, stream>>>(Qg, Kg, VgT, Og, Lsb);
  ln_gather<<<dim3(16384), 256, 0, stream>>>(Og, Lsb, lng, lnb, xln);
  out_gemm<<<dim3(128, 6), 256, 0, stream>>>(xln, wob, bo, (float*)d_out);
}

// Round 3
// 424.159 us; speedup vs baseline: 1.4258x; 1.0452x over previous
//
#include <hip/hip_runtime.h>
#include <hip/hip_bf16.h>
#include <stdint.h>

typedef unsigned int uint32;
typedef unsigned short u16;
typedef __attribute__((ext_vector_type(4))) float f32x4;
typedef __attribute__((ext_vector_type(16))) float f32x16;
typedef __attribute__((ext_vector_type(8))) __bf16 bf16x8;
typedef __attribute__((ext_vector_type(8))) short i16x8;
typedef __attribute__((ext_vector_type(4))) short i16x4;
typedef __attribute__((ext_vector_type(4))) uint32 u32x4;

#define DEVINL static __device__ __forceinline__

DEVINL u16 f2bf(float f){
  uint32 u = __builtin_bit_cast(uint32, f);
  return (u16)((u + 0x7fffu + ((u >> 16) & 1u)) >> 16);  // RNE
}

DEVINL uint32 cvtpk(float lo, float hi){
  uint32 r;
  asm("v_cvt_pk_bf16_f32 %0, %1, %2" : "=v"(r) : "v"(lo), "v"(hi));
  return r;
}

// vdst.hi32lanes <-> vsrc.lo32lanes
DEVINL void permswap(uint32 &a, uint32 &b){
  asm volatile("s_nop 1\n\tv_permlane32_swap_b32 %0, %1" : "+v"(a), "+v"(b));
}

DEVINL f32x4 mfma16(bf16x8 a, bf16x8 b, f32x4 c){
  return __builtin_amdgcn_mfma_f32_16x16x32_bf16(a, b, c, 0, 0, 0);
}
DEVINL f32x16 mfma32(bf16x8 a, bf16x8 b, f32x16 c){
  return __builtin_amdgcn_mfma_f32_32x32x16_bf16(a, b, c, 0, 0, 0);
}
DEVINL f32x16 zero16(){
  f32x16 z;
  #pragma unroll
  for (int r = 0; r < 16; ++r) z[r] = 0.f;
  return z;
}

static constexpr int LDK = 40;              // padded LDS K-stride (bf16 elems)
static constexpr size_t ISTR = 2048 * 64;   // elems per attention instance
static constexpr float QSCALE = 0.18033688011112042f;  // log2(e)/8 folded into Q

// ---------------- weight f32 -> bf16 ----------------
__global__ void cvt_w(const float* __restrict__ src, u16* __restrict__ dst, int n4){
  int i = blockIdx.x * 256 + threadIdx.x;
  if (i < n4){
    f32x4 v = *(const f32x4*)(src + (size_t)i * 4);
    u16 o[4];
    #pragma unroll
    for (int j = 0; j < 4; ++j) o[j] = f2bf(v[j]);
    *(i16x4*)(dst + (size_t)i * 4) = *(const i16x4*)o;
  }
}

// ---------------- QKV projection GEMM, scatter-to-gathered epilogue ----------------
__global__ __launch_bounds__(256) void qkv_gemm(
    const float* __restrict__ X, const u16* __restrict__ W,
    const float* __restrict__ bias, u16* __restrict__ Yg,
    float scale, int tmode)
{
  __shared__ u16 As[128 * LDK];
  __shared__ u16 Bs[128 * LDK];
  const int tid = threadIdx.x;
  const int l = tid & 63, w = tid >> 6;
  const int l15 = l & 15, lh = l >> 4;
  const int wr = w >> 1, wc = w & 1;
  const int row0 = blockIdx.x * 128, col0 = blockIdx.y * 128;
  const int sr = tid >> 1, skc = (tid & 1) * 16;

  const float* ap = X + (size_t)(row0 + sr) * 768 + skc;
  const u16*   bp = W + (size_t)(col0 + sr) * 768 + skc;

  f32x4 acc[4][4];
  #pragma unroll
  for (int i = 0; i < 4; ++i)
    #pragma unroll
    for (int j = 0; j < 4; ++j) acc[i][j] = f32x4{0.f, 0.f, 0.f, 0.f};

  f32x4 ra0, ra1, ra2, ra3; i16x8 rb0, rb1;
  ra0 = *(const f32x4*)(ap);      ra1 = *(const f32x4*)(ap + 4);
  ra2 = *(const f32x4*)(ap + 8);  ra3 = *(const f32x4*)(ap + 12);
  rb0 = *(const i16x8*)(bp);      rb1 = *(const i16x8*)(bp + 8);

  for (int ks = 0; ks < 24; ++ks) {
    __syncthreads();
    u32x4 w0 = { cvtpk(ra0[0], ra0[1]), cvtpk(ra0[2], ra0[3]),
                 cvtpk(ra1[0], ra1[1]), cvtpk(ra1[2], ra1[3]) };
    u32x4 w1 = { cvtpk(ra2[0], ra2[1]), cvtpk(ra2[2], ra2[3]),
                 cvtpk(ra3[0], ra3[1]), cvtpk(ra3[2], ra3[3]) };
    *(i16x8*)&As[sr * LDK + skc]     = __builtin_bit_cast(i16x8, w0);
    *(i16x8*)&As[sr * LDK + skc + 8] = __builtin_bit_cast(i16x8, w1);
    *(i16x8*)&Bs[sr * LDK + skc]     = rb0;
    *(i16x8*)&Bs[sr * LDK + skc + 8] = rb1;
    __syncthreads();
    if (ks < 23) {
      const float* ap2 = ap + (ks + 1) * 32;
      const u16*   bp2 = bp + (ks + 1) * 32;
      ra0 = *(const f32x4*)(ap2);      ra1 = *(const f32x4*)(ap2 + 4);
      ra2 = *(const f32x4*)(ap2 + 8);  ra3 = *(const f32x4*)(ap2 + 12);
      rb0 = *(const i16x8*)(bp2);      rb1 = *(const i16x8*)(bp2 + 8);
    }
    bf16x8 af[4], bfr[4];
    #pragma unroll
    for (int mi = 0; mi < 4; ++mi)
      af[mi] = *(const bf16x8*)&As[(wr * 64 + mi * 16 + l15) * LDK + lh * 8];
    #pragma unroll
    for (int ni = 0; ni < 4; ++ni)
      bfr[ni] = *(const bf16x8*)&Bs[(wc * 64 + ni * 16 + l15) * LDK + lh * 8];
    #pragma unroll
    for (int mi = 0; mi < 4; ++mi)
      #pragma unroll
      for (int ni = 0; ni < 4; ++ni)
        acc[mi][ni] = mfma16(af[mi], bfr[ni], acc[mi][ni]);
  }

  #pragma unroll
  for (int ni = 0; ni < 4; ++ni) {
    const int e = col0 + wc * 64 + ni * 16 + l15;
    const int h = e >> 6, d = e & 63;
    const int grp = h >> 2, hg = h & 3;
    const int instB = (grp == 0) ? 0 : (grp == 1) ? 32 : 48;
    const float bia = bias[e];
    #pragma unroll
    for (int mi = 0; mi < 4; ++mi) {
      #pragma unroll
      for (int r = 0; r < 4; ++r) {
        const int row = row0 + wr * 64 + mi * 16 + lh * 4 + r;
        const int b = row >> 13, nn = row & 8191;
        const int p = nn & ((2048 << grp) - 1);
        if ((p & ((1 << grp) - 1)) != grp) continue;   // off dilation grid
        const int seg = nn >> (11 + grp);
        const int t = (p - grp) >> grp;
        const int inst = instB + ((b * (4 >> grp) + seg) << 2) + hg;
        const u16 val = f2bf((acc[mi][ni][r] + bia) * scale);
        if (tmode == 0) Yg[(size_t)inst * ISTR + (size_t)t * 64 + d] = val;
        else            Yg[(size_t)inst * ISTR + (size_t)d * 2048 + t] = val;
      }
    }
  }
}

// ---------------- dilated flash attention: 1 wave/block, split-K 2-way ----------------
// wave = 32 q rows, K-range = 1024; no-max softmax; row-sum via MFMA-with-ones.
__global__ __launch_bounds__(64) void dil_attn(
    const u16* __restrict__ Qg, const u16* __restrict__ Kg,
    const u16* __restrict__ VgT, uint32* __restrict__ Op32, float* __restrict__ Ls)
{
  const int l = threadIdx.x;
  const int l31 = l & 31, hi = l >> 5;
  // XCD-bijective swizzle: 7168 = 8 XCD x 896; 7 instances (128 blocks) per XCD
  const int id = blockIdx.x;
  const int nid = (id & 7) * 896 + (id >> 3);
  const int inst = nid >> 7, rem = nid & 127;
  const int qt = rem >> 1, kh = rem & 1;
  const size_t ibase = (size_t)inst * ISTR;
  const int qbase = qt * 32;
  const int k0 = kh * 1024;

  // Q as B-frag (pre-scaled by log2(e)/8): lane holds Q[q=l31][d=m*16+hi*8+j]
  const u16* qlane = Qg + ibase + (size_t)(qbase + l31) * 64 + hi * 8;
  const bf16x8 qf0 = *(const bf16x8*)(qlane);
  const bf16x8 qf1 = *(const bf16x8*)(qlane + 16);
  const bf16x8 qf2 = *(const bf16x8*)(qlane + 32);
  const bf16x8 qf3 = *(const bf16x8*)(qlane + 48);

  const u16* klane  = Kg  + ibase + (size_t)l31 * 64 + hi * 8;
  const u16* vlane0 = VgT + ibase + (size_t)l31 * 2048 + hi * 8;
  const u16* vlane1 = vlane0 + (size_t)32 * 2048;

  f32x16 acc0 = zero16(), acc1 = zero16(), rs = zero16();
  const bf16x8 ones = __builtin_bit_cast(bf16x8,
      u32x4{0x3F803F80u, 0x3F803F80u, 0x3F803F80u, 0x3F803F80u});

  // preload first K tile
  const u16* kp0 = klane + (size_t)k0 * 64;
  bf16x8 kc0 = *(const bf16x8*)(kp0);
  bf16x8 kc1 = *(const bf16x8*)(kp0 + 16);
  bf16x8 kc2 = *(const bf16x8*)(kp0 + 32);
  bf16x8 kc3 = *(const bf16x8*)(kp0 + 48);
  bf16x8 kn0, kn1, kn2, kn3;

  for (int kk = k0; kk < k0 + 1024; kk += 64) {
    // ================= tile A: [kk, kk+32) using kc =================
    {
      const u16* vp0 = vlane0 + kk;
      const u16* vp1 = vlane1 + kk;
      bf16x8 v00 = *(const bf16x8*)(vp0);
      bf16x8 v01 = *(const bf16x8*)(vp0 + 16);
      bf16x8 v10 = *(const bf16x8*)(vp1);
      bf16x8 v11 = *(const bf16x8*)(vp1 + 16);

      f32x16 sT = zero16();
      sT = mfma32(kc0, qf0, sT);
      sT = mfma32(kc1, qf1, sT);
      sT = mfma32(kc2, qf2, sT);
      sT = mfma32(kc3, qf3, sT);

      // prefetch K for tile B
      const u16* kp = klane + (size_t)(kk + 32) * 64;
      kn0 = *(const bf16x8*)(kp);
      kn1 = *(const bf16x8*)(kp + 16);
      kn2 = *(const bf16x8*)(kp + 32);
      kn3 = *(const bf16x8*)(kp + 48);

      #pragma unroll
      for (int r = 0; r < 16; ++r) sT[r] = exp2f(sT[r]);
      uint32 cw0 = cvtpk(sT[0],  sT[1]),  cw1 = cvtpk(sT[2],  sT[3]);
      uint32 cw2 = cvtpk(sT[4],  sT[5]),  cw3 = cvtpk(sT[6],  sT[7]);
      uint32 cw4 = cvtpk(sT[8],  sT[9]),  cw5 = cvtpk(sT[10], sT[11]);
      uint32 cw6 = cvtpk(sT[12], sT[13]), cw7 = cvtpk(sT[14], sT[15]);
      permswap(cw0, cw2); permswap(cw1, cw3);
      permswap(cw4, cw6); permswap(cw5, cw7);
      bf16x8 pa0 = __builtin_bit_cast(bf16x8, u32x4{cw0, cw1, cw2, cw3});
      bf16x8 pa1 = __builtin_bit_cast(bf16x8, u32x4{cw4, cw5, cw6, cw7});

      rs   = mfma32(pa0, ones, rs);
      rs   = mfma32(pa1, ones, rs);
      acc0 = mfma32(pa0, v00, acc0);
      acc0 = mfma32(pa1, v01, acc0);
      acc1 = mfma32(pa0, v10, acc1);
      acc1 = mfma32(pa1, v11, acc1);
    }
    // ================= tile B: [kk+32, kk+64) using kn =================
    {
      const int kk2 = kk + 32;
      const u16* vp0 = vlane0 + kk2;
      const u16* vp1 = vlane1 + kk2;
      bf16x8 v00 = *(const bf16x8*)(vp0);
      bf16x8 v01 = *(const bf16x8*)(vp0 + 16);
      bf16x8 v10 = *(const bf16x8*)(vp1);
      bf16x8 v11 = *(const bf16x8*)(vp1 + 16);

      f32x16 sT = zero16();
      sT = mfma32(kn0, qf0, sT);
      sT = mfma32(kn1, qf1, sT);
      sT = mfma32(kn2, qf2, sT);
      sT = mfma32(kn3, qf3, sT);

      // prefetch K for next tile A (wraps within [k0,k0+1024) on last iter)
      const int nk = k0 + ((kk2 + 32 - k0) & 1023);
      const u16* kp = klane + (size_t)nk * 64;
      kc0 = *(const bf16x8*)(kp);
      kc1 = *(const bf16x8*)(kp + 16);
      kc2 = *(const bf16x8*)(kp + 32);
      kc3 = *(const bf16x8*)(kp + 48);

      #pragma unroll
      for (int r = 0; r < 16; ++r) sT[r] = exp2f(sT[r]);
      uint32 cw0 = cvtpk(sT[0],  sT[1]),  cw1 = cvtpk(sT[2],  sT[3]);
      uint32 cw2 = cvtpk(sT[4],  sT[5]),  cw3 = cvtpk(sT[6],  sT[7]);
      uint32 cw4 = cvtpk(sT[8],  sT[9]),  cw5 = cvtpk(sT[10], sT[11]);
      uint32 cw6 = cvtpk(sT[12], sT[13]), cw7 = cvtpk(sT[14], sT[15]);
      permswap(cw0, cw2); permswap(cw1, cw3);
      permswap(cw4, cw6); permswap(cw5, cw7);
      bf16x8 pa0 = __builtin_bit_cast(bf16x8, u32x4{cw0, cw1, cw2, cw3});
      bf16x8 pa1 = __builtin_bit_cast(bf16x8, u32x4{cw4, cw5, cw6, cw7});

      rs   = mfma32(pa0, ones, rs);
      rs   = mfma32(pa1, ones, rs);
      acc0 = mfma32(pa0, v00, acc0);
      acc0 = mfma32(pa1, v01, acc0);
      acc1 = mfma32(pa0, v10, acc1);
      acc1 = mfma32(pa1, v11, acc1);
    }
  }

  // partial row sums: every column of rs identical; lanes 0 and 32 cover all 32 q rows
  if (l31 == 0) {
    float* lsp = Ls + ((size_t)kh * 56 + inst) * 2048 + qbase;
    #pragma unroll
    for (int r = 0; r < 16; ++r) {
      const int qrow = (r & 3) + 8 * (r >> 2) + 4 * hi;
      lsp[qrow] = rs[r];
    }
  }
  // partial O, bf16-packed: word {O[t][d], O[t][d+32]} at [(inst*2048+t)*32 + d]
  uint32* op = Op32 + (size_t)kh * (56u * 2048u * 32u)
                    + ((size_t)inst * 2048 + qbase) * 32 + l31;
  #pragma unroll
  for (int r = 0; r < 16; ++r) {
    const int qrow = (r & 3) + 8 * (r >> 2) + 4 * hi;
    op[(size_t)qrow * 32] = cvtpk(acc0[r], acc1[r]);
  }
}

// ---------------- gather + combine split-K + normalize + LayerNorm -> xln ----------------
__global__ __launch_bounds__(256) void ln_gather(
    const uint32* __restrict__ Op32, const float* __restrict__ Ls,
    const float* __restrict__ gamma, const float* __restrict__ beta,
    u16* __restrict__ xln)
{
  const int row = blockIdx.x;            // 0..16383
  const int b = row >> 13, nn = row & 8191;
  const int tid = threadIdx.x;
  const size_t KHOFF = 56u * 2048u * 32u;
  float v[3];
  #pragma unroll
  for (int j = 0; j < 3; ++j) {
    const int e = tid + j * 256;
    const int h = e >> 6, d = e & 63;
    const int grp = h >> 2, hg = h & 3;
    const int p = nn & ((2048 << grp) - 1);
    float val = 0.f;
    if ((p & ((1 << grp) - 1)) == grp) {
      const int seg = nn >> (11 + grp);
      const int instB = (grp == 0) ? 0 : (grp == 1) ? 32 : 48;
      const int inst = instB + ((b * (4 >> grp) + seg) << 2) + hg;
      const int t = (p - grp) >> grp;
      const size_t wbase = ((size_t)inst * 2048 + t) * 32 + (d & 31);
      const uint32 w0 = Op32[wbase];
      const uint32 w1 = Op32[wbase + KHOFF];
      const float o0 = __builtin_bit_cast(float, d < 32 ? (w0 << 16) : (w0 & 0xFFFF0000u));
      const float o1 = __builtin_bit_cast(float, d < 32 ? (w1 << 16) : (w1 & 0xFFFF0000u));
      const float s = Ls[(size_t)inst * 2048 + t] + Ls[(size_t)(56 * 2048) + inst * 2048 + t];
      val = (o0 + o1) * (1.0f / (3.0f * s));
    }
    v[j] = val;
  }
  float s = v[0] + v[1] + v[2];
  float q = v[0]*v[0] + v[1]*v[1] + v[2]*v[2];
  #pragma unroll
  for (int off = 1; off < 64; off <<= 1) { s += __shfl_xor(s, off); q += __shfl_xor(q, off); }
  __shared__ float red[8];
  const int w = tid >> 6, l = tid & 63;
  if (l == 0) { red[w] = s; red[4 + w] = q; }
  __syncthreads();
  s = red[0] + red[1] + red[2] + red[3];
  q = red[4] + red[5] + red[6] + red[7];
  const float mu = s * (1.f / 768.f);
  const float var = q * (1.f / 768.f) - mu * mu;
  const float rs = rsqrtf(var + 1e-5f);
  #pragma unroll
  for (int j = 0; j < 3; ++j) {
    const int e = tid + j * 256;
    xln[(size_t)row * 768 + e] = f2bf((v[j] - mu) * rs * gamma[e] + beta[e]);
  }
}

// ---------------- output projection GEMM (bf16 A, f32 out) ----------------
__global__ __launch_bounds__(256) void out_gemm(
    const u16* __restrict__ Xb, const u16* __restrict__ W,
    const float* __restrict__ bias, float* __restrict__ out)
{
  __shared__ u16 As[128 * LDK];
  __shared__ u16 Bs[128 * LDK];
  const int tid = threadIdx.x;
  const int l = tid & 63, w = tid >> 6;
  const int l15 = l & 15, lh = l >> 4;
  const int wr = w >> 1, wc = w & 1;
  const int row0 = blockIdx.x * 128, col0 = blockIdx.y * 128;
  const int sr = tid >> 1, skc = (tid & 1) * 16;

  const u16* ap = Xb + (size_t)(row0 + sr) * 768 + skc;
  const u16* bp = W + (size_t)(col0 + sr) * 768 + skc;

  f32x4 acc[4][4];
  #pragma unroll
  for (int i = 0; i < 4; ++i)
    #pragma unroll
    for (int j = 0; j < 4; ++j) acc[i][j] = f32x4{0.f, 0.f, 0.f, 0.f};

  i16x8 ra0, ra1, rb0, rb1;
  ra0 = *(const i16x8*)(ap); ra1 = *(const i16x8*)(ap + 8);
  rb0 = *(const i16x8*)(bp); rb1 = *(const i16x8*)(bp + 8);

  for (int ks = 0; ks < 24; ++ks) {
    __syncthreads();
    *(i16x8*)&As[sr * LDK + skc]     = ra0;
    *(i16x8*)&As[sr * LDK + skc + 8] = ra1;
    *(i16x8*)&Bs[sr * LDK + skc]     = rb0;
    *(i16x8*)&Bs[sr * LDK + skc + 8] = rb1;
    __syncthreads();
    if (ks < 23) {
      const u16* ap2 = ap + (ks + 1) * 32;
      const u16* bp2 = bp + (ks + 1) * 32;
      ra0 = *(const i16x8*)(ap2); ra1 = *(const i16x8*)(ap2 + 8);
      rb0 = *(const i16x8*)(bp2); rb1 = *(const i16x8*)(bp2 + 8);
    }
    bf16x8 af[4], bfr[4];
    #pragma unroll
    for (int mi = 0; mi < 4; ++mi)
      af[mi] = *(const bf16x8*)&As[(wr * 64 + mi * 16 + l15) * LDK + lh * 8];
    #pragma unroll
    for (int ni = 0; ni < 4; ++ni)
      bfr[ni] = *(const bf16x8*)&Bs[(wc * 64 + ni * 16 + l15) * LDK + lh * 8];
    #pragma unroll
    for (int mi = 0; mi < 4; ++mi)
      #pragma unroll
      for (int ni = 0; ni < 4; ++ni)
        acc[mi][ni] = mfma16(af[mi], bfr[ni], acc[mi][ni]);
  }

  #pragma unroll
  for (int ni = 0; ni < 4; ++ni) {
    const int e = col0 + wc * 64 + ni * 16 + l15;
    const float bia = bias[e];
    #pragma unroll
    for (int mi = 0; mi < 4; ++mi) {
      #pragma unroll
      for (int r = 0; r < 4; ++r) {
        const int row = row0 + wr * 64 + mi * 16 + lh * 4 + r;
        out[(size_t)row * 768 + e] = acc[mi][ni][r] + bia;
      }
    }
  }
}

extern "C" void kernel_launch(void* const* d_in, const int* in_sizes, int n_in,
                              void* d_out, int out_size, void* d_ws, size_t ws_size,
                              hipStream_t stream) {
  const float* query = (const float*)d_in[0];
  const float* key_  = (const float*)d_in[1];
  const float* value = (const float*)d_in[2];
  const float* Wq = (const float*)d_in[3];
  const float* bq = (const float*)d_in[4];
  const float* Wk = (const float*)d_in[5];
  const float* bk = (const float*)d_in[6];
  const float* Wv = (const float*)d_in[7];
  const float* bv = (const float*)d_in[8];
  const float* Wo = (const float*)d_in[9];
  const float* bo = (const float*)d_in[10];
  const float* lng = (const float*)d_in[11];
  const float* lnb = (const float*)d_in[12];

  char* ws = (char*)d_ws;
  size_t off = 0;
  auto alloc = [&](size_t bytes) { size_t o = off; off += (bytes + 255) & ~(size_t)255; return o; };
  const size_t WB = 768 * 768 * 2;           // bf16 weight bytes
  const size_t GB = (size_t)56 * ISTR * 2;   // gathered bf16 bytes
  u16* wqb = (u16*)(ws + alloc(WB));
  u16* wkb = (u16*)(ws + alloc(WB));
  u16* wvb = (u16*)(ws + alloc(WB));
  u16* wob = (u16*)(ws + alloc(WB));
  u16* Qg  = (u16*)(ws + alloc(GB));
  u16* Kg  = (u16*)(ws + alloc(GB));
  u16* VgT = (u16*)(ws + alloc(GB));
  uint32* Op32 = (uint32*)(ws + alloc((size_t)2 * 56 * 2048 * 32 * 4));
  float* Lsb  = (float*)(ws + alloc((size_t)2 * 56 * 2048 * 4));
  u16* xln = (u16*)(ws + alloc((size_t)16384 * 768 * 2));

  const int n4 = 768 * 768 / 4;
  cvt_w<<<dim3(576), 256, 0, stream>>>(Wq, wqb, n4);
  cvt_w<<<dim3(576), 256, 0, stream>>>(Wk, wkb, n4);
  cvt_w<<<dim3(576), 256, 0, stream>>>(Wv, wvb, n4);
  cvt_w<<<dim3(576), 256, 0, stream>>>(Wo, wob, n4);

  qkv_gemm<<<dim3(128, 6), 256, 0, stream>>>(query, wqb, bq, Qg, QSCALE, 0);
  qkv_gemm<<<dim3(128, 6), 256, 0, stream>>>(key_,  wkb, bk, Kg, 1.0f, 0);
  qkv_gemm<<<dim3(128, 6), 256, 0, stream>>>(value, wvb, bv, VgT, 1.0f, 1);

  dil_attn<<<dim3(7168), 64, 0, stream>>>(Qg, Kg, VgT, Op32, Lsb);
  ln_gather<<<dim3(16384), 256, 0, stream>>>(Op32, Lsb, lng, lnb, xln);
  out_gemm<<<dim3(128, 6), 256, 0, stream>>>(xln, wob, bo, (float*)d_out);
}

// Round 4
// 324.081 us; speedup vs baseline: 1.8661x; 1.3088x over previous
//
#include <hip/hip_runtime.h>
#include <hip/hip_bf16.h>
#include <stdint.h>

typedef unsigned int uint32;
typedef unsigned short u16;
typedef __attribute__((ext_vector_type(4))) float f32x4;
typedef __attribute__((ext_vector_type(16))) float f32x16;
typedef __attribute__((ext_vector_type(8))) __bf16 bf16x8;
typedef __attribute__((ext_vector_type(8))) short i16x8;
typedef __attribute__((ext_vector_type(4))) short i16x4;
typedef __attribute__((ext_vector_type(4))) uint32 u32x4;

#define DEVINL static __device__ __forceinline__

DEVINL u16 f2bf(float f){
  uint32 u = __builtin_bit_cast(uint32, f);
  return (u16)((u + 0x7fffu + ((u >> 16) & 1u)) >> 16);  // RNE
}

DEVINL uint32 cvtpk(float lo, float hi){
  uint32 r;
  asm("v_cvt_pk_bf16_f32 %0, %1, %2" : "=v"(r) : "v"(lo), "v"(hi));
  return r;
}

// vdst.hi32lanes <-> vsrc.lo32lanes
DEVINL void permswap(uint32 &a, uint32 &b){
  asm volatile("s_nop 1\n\tv_permlane32_swap_b32 %0, %1" : "+v"(a), "+v"(b));
}

DEVINL f32x4 mfma16(bf16x8 a, bf16x8 b, f32x4 c){
  return __builtin_amdgcn_mfma_f32_16x16x32_bf16(a, b, c, 0, 0, 0);
}
DEVINL f32x16 mfma32(bf16x8 a, bf16x8 b, f32x16 c){
  return __builtin_amdgcn_mfma_f32_32x32x16_bf16(a, b, c, 0, 0, 0);
}
DEVINL f32x16 zero16(){
  f32x16 z;
  #pragma unroll
  for (int r = 0; r < 16; ++r) z[r] = 0.f;
  return z;
}

// async global->LDS, 16B per lane; LDS dest is wave-uniform base + lane*16
DEVINL void gload16(const u16* g, u16* l){
  __builtin_amdgcn_global_load_lds(
      (const __attribute__((address_space(1))) uint32*)g,
      (__attribute__((address_space(3))) uint32*)l, 16, 0, 0);
}

static constexpr int LDK = 40;              // padded LDS K-stride (bf16 elems)
static constexpr size_t ISTR = 2048 * 64;   // elems per attention instance
static constexpr float QSCALE = 0.18033688011112042f;  // log2(e)/8 folded into Q

// ---------------- weight f32 -> bf16 ----------------
__global__ void cvt_w(const float* __restrict__ src, u16* __restrict__ dst, int n4){
  int i = blockIdx.x * 256 + threadIdx.x;
  if (i < n4){
    f32x4 v = *(const f32x4*)(src + (size_t)i * 4);
    u16 o[4];
    #pragma unroll
    for (int j = 0; j < 4; ++j) o[j] = f2bf(v[j]);
    *(i16x4*)(dst + (size_t)i * 4) = *(const i16x4*)o;
  }
}

// ---------------- QKV projection GEMM, scatter-to-gathered epilogue ----------------
__global__ __launch_bounds__(256) void qkv_gemm(
    const float* __restrict__ X, const u16* __restrict__ W,
    const float* __restrict__ bias, u16* __restrict__ Yg,
    float scale, int tmode)
{
  __shared__ u16 As[128 * LDK];
  __shared__ u16 Bs[128 * LDK];
  const int tid = threadIdx.x;
  const int l = tid & 63, w = tid >> 6;
  const int l15 = l & 15, lh = l >> 4;
  const int wr = w >> 1, wc = w & 1;
  const int row0 = blockIdx.x * 128, col0 = blockIdx.y * 128;
  const int sr = tid >> 1, skc = (tid & 1) * 16;

  const float* ap = X + (size_t)(row0 + sr) * 768 + skc;
  const u16*   bp = W + (size_t)(col0 + sr) * 768 + skc;

  f32x4 acc[4][4];
  #pragma unroll
  for (int i = 0; i < 4; ++i)
    #pragma unroll
    for (int j = 0; j < 4; ++j) acc[i][j] = f32x4{0.f, 0.f, 0.f, 0.f};

  f32x4 ra0, ra1, ra2, ra3; i16x8 rb0, rb1;
  ra0 = *(const f32x4*)(ap);      ra1 = *(const f32x4*)(ap + 4);
  ra2 = *(const f32x4*)(ap + 8);  ra3 = *(const f32x4*)(ap + 12);
  rb0 = *(const i16x8*)(bp);      rb1 = *(const i16x8*)(bp + 8);

  for (int ks = 0; ks < 24; ++ks) {
    __syncthreads();
    u32x4 w0 = { cvtpk(ra0[0], ra0[1]), cvtpk(ra0[2], ra0[3]),
                 cvtpk(ra1[0], ra1[1]), cvtpk(ra1[2], ra1[3]) };
    u32x4 w1 = { cvtpk(ra2[0], ra2[1]), cvtpk(ra2[2], ra2[3]),
                 cvtpk(ra3[0], ra3[1]), cvtpk(ra3[2], ra3[3]) };
    *(i16x8*)&As[sr * LDK + skc]     = __builtin_bit_cast(i16x8, w0);
    *(i16x8*)&As[sr * LDK + skc + 8] = __builtin_bit_cast(i16x8, w1);
    *(i16x8*)&Bs[sr * LDK + skc]     = rb0;
    *(i16x8*)&Bs[sr * LDK + skc + 8] = rb1;
    __syncthreads();
    if (ks < 23) {
      const float* ap2 = ap + (ks + 1) * 32;
      const u16*   bp2 = bp + (ks + 1) * 32;
      ra0 = *(const f32x4*)(ap2);      ra1 = *(const f32x4*)(ap2 + 4);
      ra2 = *(const f32x4*)(ap2 + 8);  ra3 = *(const f32x4*)(ap2 + 12);
      rb0 = *(const i16x8*)(bp2);      rb1 = *(const i16x8*)(bp2 + 8);
    }
    bf16x8 af[4], bfr[4];
    #pragma unroll
    for (int mi = 0; mi < 4; ++mi)
      af[mi] = *(const bf16x8*)&As[(wr * 64 + mi * 16 + l15) * LDK + lh * 8];
    #pragma unroll
    for (int ni = 0; ni < 4; ++ni)
      bfr[ni] = *(const bf16x8*)&Bs[(wc * 64 + ni * 16 + l15) * LDK + lh * 8];
    #pragma unroll
    for (int mi = 0; mi < 4; ++mi)
      #pragma unroll
      for (int ni = 0; ni < 4; ++ni)
        acc[mi][ni] = mfma16(af[mi], bfr[ni], acc[mi][ni]);
  }

  #pragma unroll
  for (int ni = 0; ni < 4; ++ni) {
    const int e = col0 + wc * 64 + ni * 16 + l15;
    const int h = e >> 6, d = e & 63;
    const int grp = h >> 2, hg = h & 3;
    const int instB = (grp == 0) ? 0 : (grp == 1) ? 32 : 48;
    const float bia = bias[e];
    #pragma unroll
    for (int mi = 0; mi < 4; ++mi) {
      #pragma unroll
      for (int r = 0; r < 4; ++r) {
        const int row = row0 + wr * 64 + mi * 16 + lh * 4 + r;
        const int b = row >> 13, nn = row & 8191;
        const int p = nn & ((2048 << grp) - 1);
        if ((p & ((1 << grp) - 1)) != grp) continue;   // off dilation grid
        const int seg = nn >> (11 + grp);
        const int t = (p - grp) >> grp;
        const int inst = instB + ((b * (4 >> grp) + seg) << 2) + hg;
        const u16 val = f2bf((acc[mi][ni][r] + bia) * scale);
        if (tmode == 0) Yg[(size_t)inst * ISTR + (size_t)t * 64 + d] = val;
        else            Yg[(size_t)inst * ISTR + (size_t)d * 2048 + t] = val;
      }
    }
  }
}

// ---------------- dilated flash attention: 4 waves/block, LDS-staged K/V ----------------
// block covers 128 q rows (wave w: 32), full K range 2048 in 64-wide double-buffered tiles.
__global__ __launch_bounds__(256) void dil_attn(
    const u16* __restrict__ Qg, const u16* __restrict__ Kg,
    const u16* __restrict__ VgT, uint32* __restrict__ Op32, float* __restrict__ Ls)
{
  __shared__ u16 Kb[2][64 * 64];
  __shared__ u16 Vb[2][64 * 64];
  const int tid = threadIdx.x;
  const int w = tid >> 6, l = tid & 63;
  const int l31 = l & 31, hi = l >> 5;
  // XCD-bijective swizzle: 896 = 8 XCD x 112; 7 instances (16 blocks) per XCD
  const int id = blockIdx.x;
  const int nid = (id & 7) * 112 + (id >> 3);
  const int inst = nid >> 4, qb = nid & 15;
  const size_t ibase = (size_t)inst * ISTR;
  const int qbase = qb * 128 + w * 32;

  // Q as B-frag (pre-scaled by log2(e)/8): lane holds Q[q=l31][d=m*16+hi*8+j]
  const u16* qlane = Qg + ibase + (size_t)(qbase + l31) * 64 + hi * 8;
  const bf16x8 qf0 = *(const bf16x8*)(qlane);
  const bf16x8 qf1 = *(const bf16x8*)(qlane + 16);
  const bf16x8 qf2 = *(const bf16x8*)(qlane + 32);
  const bf16x8 qf3 = *(const bf16x8*)(qlane + 48);

  // staging: lane li writes LDS halfwords [base + li*8, +8) (linear).
  // LDS layout (both tiles): elem (row, col) at row*64 + (col ^ ((row&7)<<3)).
  // => lane li covers row = base_row + (li>>3), col chunk = ((li&7) ^ ((li>>3)&7))<<3.
  const int srow = l >> 3;
  const int scol = ((l & 7) ^ (srow & 7)) << 3;
  const u16* kgs = Kg  + ibase + (size_t)srow * 64 + scol;    // + (k0+rb)*64
  const u16* vgs = VgT + ibase + (size_t)srow * 2048 + scol;  // + rb*2048 + k0

  f32x16 acc0 = zero16(), acc1 = zero16();
  float hs = 0.f;
  const int sxor = (l31 & 7) << 3;

  auto STAGE = [&](int buf, int k0){
    #pragma unroll
    for (int q = 0; q < 2; ++q){
      const int rb = w * 16 + q * 8;
      gload16(kgs + (size_t)(k0 + rb) * 64, &Kb[buf][rb * 64]);
      gload16(vgs + (size_t)rb * 2048 + k0, &Vb[buf][rb * 64]);
    }
  };

  STAGE(0, 0);
  asm volatile("s_waitcnt vmcnt(0)");
  __syncthreads();

  int cur = 0;
  for (int step = 0; step < 32; ++step) {
    if (step < 31) STAGE(cur ^ 1, (step + 1) << 6);
    const u16* kt = &Kb[cur][0];
    const u16* vt = &Vb[cur][0];
    #pragma unroll
    for (int s = 0; s < 2; ++s) {
      const int ksub = s * 32;
      // K frag: K[k=ksub+l31][d=m*16+hi*8 ..+8]
      const int krow = (ksub + l31) * 64;
      bf16x8 kc0 = *(const bf16x8*)&kt[krow + ((hi * 8)      ^ sxor)];
      bf16x8 kc1 = *(const bf16x8*)&kt[krow + ((16 + hi * 8) ^ sxor)];
      bf16x8 kc2 = *(const bf16x8*)&kt[krow + ((32 + hi * 8) ^ sxor)];
      bf16x8 kc3 = *(const bf16x8*)&kt[krow + ((48 + hi * 8) ^ sxor)];

      f32x16 sT = zero16();
      sT = mfma32(kc0, qf0, sT);
      sT = mfma32(kc1, qf1, sT);
      sT = mfma32(kc2, qf2, sT);
      sT = mfma32(kc3, qf3, sT);

      #pragma unroll
      for (int r = 0; r < 16; ++r) sT[r] = exp2f(sT[r]);
      // rowsum (q = l31 is lane-local)
      float s0 = (sT[0] + sT[1]) + (sT[2] + sT[3]);
      float s1 = (sT[4] + sT[5]) + (sT[6] + sT[7]);
      float s2 = (sT[8] + sT[9]) + (sT[10] + sT[11]);
      float s3 = (sT[12] + sT[13]) + (sT[14] + sT[15]);
      hs += (s0 + s1) + (s2 + s3);

      // P (C-layout) -> A-frag via cvt_pk + permlane32_swap  [T12]
      uint32 cw0 = cvtpk(sT[0],  sT[1]),  cw1 = cvtpk(sT[2],  sT[3]);
      uint32 cw2 = cvtpk(sT[4],  sT[5]),  cw3 = cvtpk(sT[6],  sT[7]);
      uint32 cw4 = cvtpk(sT[8],  sT[9]),  cw5 = cvtpk(sT[10], sT[11]);
      uint32 cw6 = cvtpk(sT[12], sT[13]), cw7 = cvtpk(sT[14], sT[15]);
      permswap(cw0, cw2); permswap(cw1, cw3);
      permswap(cw4, cw6); permswap(cw5, cw7);
      bf16x8 pa0 = __builtin_bit_cast(bf16x8, u32x4{cw0, cw1, cw2, cw3});
      bf16x8 pa1 = __builtin_bit_cast(bf16x8, u32x4{cw4, cw5, cw6, cw7});

      // V frags: V[k=ksub+koff+hi*8 ..+8][d=l31 / l31+32]
      const int vr0 = l31 * 64, vr1 = (l31 + 32) * 64;
      bf16x8 v00 = *(const bf16x8*)&vt[vr0 + ((ksub + hi * 8)      ^ sxor)];
      bf16x8 v01 = *(const bf16x8*)&vt[vr0 + ((ksub + 16 + hi * 8) ^ sxor)];
      bf16x8 v10 = *(const bf16x8*)&vt[vr1 + ((ksub + hi * 8)      ^ sxor)];
      bf16x8 v11 = *(const bf16x8*)&vt[vr1 + ((ksub + 16 + hi * 8) ^ sxor)];

      acc0 = mfma32(pa0, v00, acc0);
      acc0 = mfma32(pa1, v01, acc0);
      acc1 = mfma32(pa0, v10, acc1);
      acc1 = mfma32(pa1, v11, acc1);
    }
    asm volatile("s_waitcnt vmcnt(0)");
    __syncthreads();
    cur ^= 1;
  }

  // rowsum across hi halves; store inv = 1/(3*sum)
  hs += __shfl_xor(hs, 32);
  if (hi == 0) Ls[(size_t)inst * 2048 + qbase + l31] = 1.0f / (3.0f * hs);

  // O (unnormalized, bf16-packed {d, d+32}): C row q=(r&3)+8*(r>>2)+4*hi
  uint32* op = Op32 + ((size_t)inst * 2048 + qbase) * 32 + l31;
  #pragma unroll
  for (int r = 0; r < 16; ++r) {
    const int qrow = (r & 3) + 8 * (r >> 2) + 4 * hi;
    op[(size_t)qrow * 32] = cvtpk(acc0[r], acc1[r]);
  }
}

// ---------------- gather + normalize + LayerNorm -> xln ----------------
__global__ __launch_bounds__(256) void ln_gather(
    const uint32* __restrict__ Op32, const float* __restrict__ Ls,
    const float* __restrict__ gamma, const float* __restrict__ beta,
    u16* __restrict__ xln)
{
  const int row = blockIdx.x;            // 0..16383
  const int b = row >> 13, nn = row & 8191;
  const int tid = threadIdx.x;
  float v[3];
  #pragma unroll
  for (int j = 0; j < 3; ++j) {
    const int e = tid + j * 256;
    const int h = e >> 6, d = e & 63;
    const int grp = h >> 2, hg = h & 3;
    const int p = nn & ((2048 << grp) - 1);
    float val = 0.f;
    if ((p & ((1 << grp) - 1)) == grp) {
      const int seg = nn >> (11 + grp);
      const int instB = (grp == 0) ? 0 : (grp == 1) ? 32 : 48;
      const int inst = instB + ((b * (4 >> grp) + seg) << 2) + hg;
      const int t = (p - grp) >> grp;
      const uint32 w0 = Op32[((size_t)inst * 2048 + t) * 32 + (d & 31)];
      const float o = __builtin_bit_cast(float, d < 32 ? (w0 << 16) : (w0 & 0xFFFF0000u));
      val = o * Ls[(size_t)inst * 2048 + t];
    }
    v[j] = val;
  }
  float s = v[0] + v[1] + v[2];
  float q = v[0]*v[0] + v[1]*v[1] + v[2]*v[2];
  #pragma unroll
  for (int off = 1; off < 64; off <<= 1) { s += __shfl_xor(s, off); q += __shfl_xor(q, off); }
  __shared__ float red[8];
  const int w = tid >> 6, l = tid & 63;
  if (l == 0) { red[w] = s; red[4 + w] = q; }
  __syncthreads();
  s = red[0] + red[1] + red[2] + red[3];
  q = red[4] + red[5] + red[6] + red[7];
  const float mu = s * (1.f / 768.f);
  const float var = q * (1.f / 768.f) - mu * mu;
  const float rs = rsqrtf(var + 1e-5f);
  #pragma unroll
  for (int j = 0; j < 3; ++j) {
    const int e = tid + j * 256;
    xln[(size_t)row * 768 + e] = f2bf((v[j] - mu) * rs * gamma[e] + beta[e]);
  }
}

// ---------------- output projection GEMM (bf16 A, f32 out) ----------------
__global__ __launch_bounds__(256) void out_gemm(
    const u16* __restrict__ Xb, const u16* __restrict__ W,
    const float* __restrict__ bias, float* __restrict__ out)
{
  __shared__ u16 As[128 * LDK];
  __shared__ u16 Bs[128 * LDK];
  const int tid = threadIdx.x;
  const int l = tid & 63, w = tid >> 6;
  const int l15 = l & 15, lh = l >> 4;
  const int wr = w >> 1, wc = w & 1;
  const int row0 = blockIdx.x * 128, col0 = blockIdx.y * 128;
  const int sr = tid >> 1, skc = (tid & 1) * 16;

  const u16* ap = Xb + (size_t)(row0 + sr) * 768 + skc;
  const u16* bp = W + (size_t)(col0 + sr) * 768 + skc;

  f32x4 acc[4][4];
  #pragma unroll
  for (int i = 0; i < 4; ++i)
    #pragma unroll
    for (int j = 0; j < 4; ++j) acc[i][j] = f32x4{0.f, 0.f, 0.f, 0.f};

  i16x8 ra0, ra1, rb0, rb1;
  ra0 = *(const i16x8*)(ap); ra1 = *(const i16x8*)(ap + 8);
  rb0 = *(const i16x8*)(bp); rb1 = *(const i16x8*)(bp + 8);

  for (int ks = 0; ks < 24; ++ks) {
    __syncthreads();
    *(i16x8*)&As[sr * LDK + skc]     = ra0;
    *(i16x8*)&As[sr * LDK + skc + 8] = ra1;
    *(i16x8*)&Bs[sr * LDK + skc]     = rb0;
    *(i16x8*)&Bs[sr * LDK + skc + 8] = rb1;
    __syncthreads();
    if (ks < 23) {
      const u16* ap2 = ap + (ks + 1) * 32;
      const u16* bp2 = bp + (ks + 1) * 32;
      ra0 = *(const i16x8*)(ap2); ra1 = *(const i16x8*)(ap2 + 8);
      rb0 = *(const i16x8*)(bp2); rb1 = *(const i16x8*)(bp2 + 8);
    }
    bf16x8 af[4], bfr[4];
    #pragma unroll
    for (int mi = 0; mi < 4; ++mi)
      af[mi] = *(const bf16x8*)&As[(wr * 64 + mi * 16 + l15) * LDK + lh * 8];
    #pragma unroll
    for (int ni = 0; ni < 4; ++ni)
      bfr[ni] = *(const bf16x8*)&Bs[(wc * 64 + ni * 16 + l15) * LDK + lh * 8];
    #pragma unroll
    for (int mi = 0; mi < 4; ++mi)
      #pragma unroll
      for (int ni = 0; ni < 4; ++ni)
        acc[mi][ni] = mfma16(af[mi], bfr[ni], acc[mi][ni]);
  }

  #pragma unroll
  for (int ni = 0; ni < 4; ++ni) {
    const int e = col0 + wc * 64 + ni * 16 + l15;
    const float bia = bias[e];
    #pragma unroll
    for (int mi = 0; mi < 4; ++mi) {
      #pragma unroll
      for (int r = 0; r < 4; ++r) {
        const int row = row0 + wr * 64 + mi * 16 + lh * 4 + r;
        out[(size_t)row * 768 + e] = acc[mi][ni][r] + bia;
      }
    }
  }
}

extern "C" void kernel_launch(void* const* d_in, const int* in_sizes, int n_in,
                              void* d_out, int out_size, void* d_ws, size_t ws_size,
                              hipStream_t stream) {
  const float* query = (const float*)d_in[0];
  const float* key_  = (const float*)d_in[1];
  const float* value = (const float*)d_in[2];
  const float* Wq = (const float*)d_in[3];
  const float* bq = (const float*)d_in[4];
  const float* Wk = (const float*)d_in[5];
  const float* bk = (const float*)d_in[6];
  const float* Wv = (const float*)d_in[7];
  const float* bv = (const float*)d_in[8];
  const float* Wo = (const float*)d_in[9];
  const float* bo = (const float*)d_in[10];
  const float* lng = (const float*)d_in[11];
  const float* lnb = (const float*)d_in[12];

  char* ws = (char*)d_ws;
  size_t off = 0;
  auto alloc = [&](size_t bytes) { size_t o = off; off += (bytes + 255) & ~(size_t)255; return o; };
  const size_t WB = 768 * 768 * 2;           // bf16 weight bytes
  const size_t GB = (size_t)56 * ISTR * 2;   // gathered bf16 bytes
  u16* wqb = (u16*)(ws + alloc(WB));
  u16* wkb = (u16*)(ws + alloc(WB));
  u16* wvb = (u16*)(ws + alloc(WB));
  u16* wob = (u16*)(ws + alloc(WB));
  u16* Qg  = (u16*)(ws + alloc(GB));
  u16* Kg  = (u16*)(ws + alloc(GB));
  u16* VgT = (u16*)(ws + alloc(GB));
  uint32* Op32 = (uint32*)(ws + alloc((size_t)56 * 2048 * 32 * 4));
  float* Lsb  = (float*)(ws + alloc((size_t)56 * 2048 * 4));
  u16* xln = (u16*)(ws + alloc((size_t)16384 * 768 * 2));

  const int n4 = 768 * 768 / 4;
  cvt_w<<<dim3(576), 256, 0, stream>>>(Wq, wqb, n4);
  cvt_w<<<dim3(576), 256, 0, stream>>>(Wk, wkb, n4);
  cvt_w<<<dim3(576), 256, 0, stream>>>(Wv, wvb, n4);
  cvt_w<<<dim3(576), 256, 0, stream>>>(Wo, wob, n4);

  qkv_gemm<<<dim3(128, 6), 256, 0, stream>>>(query, wqb, bq, Qg, QSCALE, 0);
  qkv_gemm<<<dim3(128, 6), 256, 0, stream>>>(key_,  wkb, bk, Kg, 1.0f, 0);
  qkv_gemm<<<dim3(128, 6), 256, 0, stream>>>(value, wvb, bv, VgT, 1.0f, 1);

  dil_attn<<<dim3(896), 256, 0, stream>>>(Qg, Kg, VgT, Op32, Lsb);
  ln_gather<<<dim3(16384), 256, 0, stream>>>(Op32, Lsb, lng, lnb, xln);
  out_gemm<<<dim3(128, 6), 256, 0, stream>>>(xln, wob, bo, (float*)d_out);
}

// Round 5
// 298.374 us; speedup vs baseline: 2.0269x; 1.0862x over previous
//
#include <hip/hip_runtime.h>
#include <hip/hip_bf16.h>
#include <stdint.h>

typedef unsigned int uint32;
typedef unsigned short u16;
typedef __attribute__((ext_vector_type(4))) float f32x4;
typedef __attribute__((ext_vector_type(16))) float f32x16;
typedef __attribute__((ext_vector_type(8))) __bf16 bf16x8;
typedef __attribute__((ext_vector_type(8))) short i16x8;
typedef __attribute__((ext_vector_type(4))) short i16x4;
typedef __attribute__((ext_vector_type(4))) uint32 u32x4;

#define DEVINL static __device__ __forceinline__

DEVINL u16 f2bf(float f){
  uint32 u = __builtin_bit_cast(uint32, f);
  return (u16)((u + 0x7fffu + ((u >> 16) & 1u)) >> 16);  // RNE
}

DEVINL uint32 cvtpk(float lo, float hi){
  uint32 r;
  asm("v_cvt_pk_bf16_f32 %0, %1, %2" : "=v"(r) : "v"(lo), "v"(hi));
  return r;
}

// vdst.hi32lanes <-> vsrc.lo32lanes
DEVINL void permswap(uint32 &a, uint32 &b){
  asm volatile("s_nop 1\n\tv_permlane32_swap_b32 %0, %1" : "+v"(a), "+v"(b));
}

DEVINL f32x4 mfma16(bf16x8 a, bf16x8 b, f32x4 c){
  return __builtin_amdgcn_mfma_f32_16x16x32_bf16(a, b, c, 0, 0, 0);
}
DEVINL f32x16 mfma32(bf16x8 a, bf16x8 b, f32x16 c){
  return __builtin_amdgcn_mfma_f32_32x32x16_bf16(a, b, c, 0, 0, 0);
}
DEVINL f32x16 zero16(){
  f32x16 z;
  #pragma unroll
  for (int r = 0; r < 16; ++r) z[r] = 0.f;
  return z;
}

// async global->LDS, 16B per lane; LDS dest is wave-uniform base + lane*16
DEVINL void gload16(const u16* g, u16* l){
  __builtin_amdgcn_global_load_lds(
      (const __attribute__((address_space(1))) uint32*)g,
      (__attribute__((address_space(3))) uint32*)l, 16, 0, 0);
}

static constexpr int LDK = 40;              // padded LDS K-stride (bf16 elems)
static constexpr size_t ISTR = 2048 * 64;   // elems per attention instance
static constexpr float QSCALE = 0.18033688011112042f;  // log2(e)/8 folded into Q

// ---------------- weight f32 -> bf16 ----------------
__global__ void cvt_w(const float* __restrict__ src, u16* __restrict__ dst, int n4){
  int i = blockIdx.x * 256 + threadIdx.x;
  if (i < n4){
    f32x4 v = *(const f32x4*)(src + (size_t)i * 4);
    u16 o[4];
    #pragma unroll
    for (int j = 0; j < 4; ++j) o[j] = f2bf(v[j]);
    *(i16x4*)(dst + (size_t)i * 4) = *(const i16x4*)o;
  }
}

// ---------------- QKV projection GEMM, scatter-to-gathered epilogue ----------------
__global__ __launch_bounds__(256) void qkv_gemm(
    const float* __restrict__ X, const u16* __restrict__ W,
    const float* __restrict__ bias, u16* __restrict__ Yg,
    float scale, int tmode)
{
  __shared__ u16 As[128 * LDK];
  __shared__ u16 Bs[128 * LDK];
  const int tid = threadIdx.x;
  const int l = tid & 63, w = tid >> 6;
  const int l15 = l & 15, lh = l >> 4;
  const int wr = w >> 1, wc = w & 1;
  const int row0 = blockIdx.x * 128, col0 = blockIdx.y * 128;
  const int sr = tid >> 1, skc = (tid & 1) * 16;

  const float* ap = X + (size_t)(row0 + sr) * 768 + skc;
  const u16*   bp = W + (size_t)(col0 + sr) * 768 + skc;

  f32x4 acc[4][4];
  #pragma unroll
  for (int i = 0; i < 4; ++i)
    #pragma unroll
    for (int j = 0; j < 4; ++j) acc[i][j] = f32x4{0.f, 0.f, 0.f, 0.f};

  f32x4 ra0, ra1, ra2, ra3; i16x8 rb0, rb1;
  ra0 = *(const f32x4*)(ap);      ra1 = *(const f32x4*)(ap + 4);
  ra2 = *(const f32x4*)(ap + 8);  ra3 = *(const f32x4*)(ap + 12);
  rb0 = *(const i16x8*)(bp);      rb1 = *(const i16x8*)(bp + 8);

  for (int ks = 0; ks < 24; ++ks) {
    __syncthreads();
    u32x4 w0 = { cvtpk(ra0[0], ra0[1]), cvtpk(ra0[2], ra0[3]),
                 cvtpk(ra1[0], ra1[1]), cvtpk(ra1[2], ra1[3]) };
    u32x4 w1 = { cvtpk(ra2[0], ra2[1]), cvtpk(ra2[2], ra2[3]),
                 cvtpk(ra3[0], ra3[1]), cvtpk(ra3[2], ra3[3]) };
    *(i16x8*)&As[sr * LDK + skc]     = __builtin_bit_cast(i16x8, w0);
    *(i16x8*)&As[sr * LDK + skc + 8] = __builtin_bit_cast(i16x8, w1);
    *(i16x8*)&Bs[sr * LDK + skc]     = rb0;
    *(i16x8*)&Bs[sr * LDK + skc + 8] = rb1;
    __syncthreads();
    if (ks < 23) {
      const float* ap2 = ap + (ks + 1) * 32;
      const u16*   bp2 = bp + (ks + 1) * 32;
      ra0 = *(const f32x4*)(ap2);      ra1 = *(const f32x4*)(ap2 + 4);
      ra2 = *(const f32x4*)(ap2 + 8);  ra3 = *(const f32x4*)(ap2 + 12);
      rb0 = *(const i16x8*)(bp2);      rb1 = *(const i16x8*)(bp2 + 8);
    }
    bf16x8 af[4], bfr[4];
    #pragma unroll
    for (int mi = 0; mi < 4; ++mi)
      af[mi] = *(const bf16x8*)&As[(wr * 64 + mi * 16 + l15) * LDK + lh * 8];
    #pragma unroll
    for (int ni = 0; ni < 4; ++ni)
      bfr[ni] = *(const bf16x8*)&Bs[(wc * 64 + ni * 16 + l15) * LDK + lh * 8];
    #pragma unroll
    for (int mi = 0; mi < 4; ++mi)
      #pragma unroll
      for (int ni = 0; ni < 4; ++ni)
        acc[mi][ni] = mfma16(af[mi], bfr[ni], acc[mi][ni]);
  }

  #pragma unroll
  for (int ni = 0; ni < 4; ++ni) {
    const int e = col0 + wc * 64 + ni * 16 + l15;
    const int h = e >> 6, d = e & 63;
    const int grp = h >> 2, hg = h & 3;
    const int instB = (grp == 0) ? 0 : (grp == 1) ? 32 : 48;
    const float bia = bias[e];
    #pragma unroll
    for (int mi = 0; mi < 4; ++mi) {
      #pragma unroll
      for (int r = 0; r < 4; ++r) {
        const int row = row0 + wr * 64 + mi * 16 + lh * 4 + r;
        const int b = row >> 13, nn = row & 8191;
        const int p = nn & ((2048 << grp) - 1);
        if ((p & ((1 << grp) - 1)) != grp) continue;   // off dilation grid
        const int seg = nn >> (11 + grp);
        const int t = (p - grp) >> grp;
        const int inst = instB + ((b * (4 >> grp) + seg) << 2) + hg;
        const u16 val = f2bf((acc[mi][ni][r] + bia) * scale);
        if (tmode == 0) Yg[(size_t)inst * ISTR + (size_t)t * 64 + d] = val;
        else            Yg[(size_t)inst * ISTR + (size_t)d * 2048 + t] = val;
      }
    }
  }
}

// ---------------- dilated flash attention: 4 waves, LDS-staged K/V, split-K 2 ----------------
// block covers 128 q rows x 1024 k; K/V in 64-wide double-buffered LDS tiles.
__global__ __launch_bounds__(256) void dil_attn(
    const u16* __restrict__ Qg, const u16* __restrict__ Kg,
    const u16* __restrict__ VgT, uint32* __restrict__ Op32, float* __restrict__ Ls)
{
  __shared__ u16 Kb[2][64 * 64];
  __shared__ u16 Vb[2][64 * 64];
  const int tid = threadIdx.x;
  const int w = tid >> 6, l = tid & 63;
  const int l31 = l & 31, hi = l >> 5;
  // XCD-bijective swizzle: 1792 = 8 XCD x 224; 7 instances (32 blocks) per XCD
  const int id = blockIdx.x;
  const int nid = (id & 7) * 224 + (id >> 3);
  const int inst = nid >> 5, rem = nid & 31;
  const int qb = rem >> 1, kh = rem & 1;
  const size_t ibase = (size_t)inst * ISTR;
  const int qbase = qb * 128 + w * 32;
  const int k0base = kh * 1024;

  // Q as B-frag (pre-scaled by log2(e)/8): lane holds Q[q=l31][d=m*16+hi*8+j]
  const u16* qlane = Qg + ibase + (size_t)(qbase + l31) * 64 + hi * 8;
  const bf16x8 qf0 = *(const bf16x8*)(qlane);
  const bf16x8 qf1 = *(const bf16x8*)(qlane + 16);
  const bf16x8 qf2 = *(const bf16x8*)(qlane + 32);
  const bf16x8 qf3 = *(const bf16x8*)(qlane + 48);

  // staging: lane li writes LDS halfwords [base + li*8, +8) (linear).
  // LDS layout (both tiles): elem (row, col) at row*64 + (col ^ ((row&7)<<3)).
  const int srow = l >> 3;
  const int scol = ((l & 7) ^ (srow & 7)) << 3;
  const u16* kgs = Kg  + ibase + (size_t)srow * 64 + scol;    // + (k0+rb)*64
  const u16* vgs = VgT + ibase + (size_t)srow * 2048 + scol;  // + rb*2048 + k0

  f32x16 acc0 = zero16(), acc1 = zero16(), rs = zero16();
  const int sxor = (l31 & 7) << 3;
  const bf16x8 ones = __builtin_bit_cast(bf16x8,
      u32x4{0x3F803F80u, 0x3F803F80u, 0x3F803F80u, 0x3F803F80u});

  auto STAGE = [&](int buf, int k0){
    #pragma unroll
    for (int q = 0; q < 2; ++q){
      const int rb = w * 16 + q * 8;
      gload16(kgs + (size_t)(k0 + rb) * 64, &Kb[buf][rb * 64]);
      gload16(vgs + (size_t)rb * 2048 + k0, &Vb[buf][rb * 64]);
    }
  };

  STAGE(0, k0base);
  asm volatile("s_waitcnt vmcnt(0)");
  __syncthreads();

  int cur = 0;
  for (int step = 0; step < 16; ++step) {
    if (step < 15) STAGE(cur ^ 1, k0base + ((step + 1) << 6));
    const u16* kt = &Kb[cur][0];
    const u16* vt = &Vb[cur][0];
    #pragma unroll
    for (int s = 0; s < 2; ++s) {
      const int ksub = s * 32;
      // K frag: K[k=ksub+l31][d=m*16+hi*8 ..+8]
      const int krow = (ksub + l31) * 64;
      bf16x8 kc0 = *(const bf16x8*)&kt[krow + ((hi * 8)      ^ sxor)];
      bf16x8 kc1 = *(const bf16x8*)&kt[krow + ((16 + hi * 8) ^ sxor)];
      bf16x8 kc2 = *(const bf16x8*)&kt[krow + ((32 + hi * 8) ^ sxor)];
      bf16x8 kc3 = *(const bf16x8*)&kt[krow + ((48 + hi * 8) ^ sxor)];

      f32x16 sT = zero16();
      sT = mfma32(kc0, qf0, sT);
      sT = mfma32(kc1, qf1, sT);
      sT = mfma32(kc2, qf2, sT);
      sT = mfma32(kc3, qf3, sT);

      #pragma unroll
      for (int r = 0; r < 16; ++r) sT[r] = __builtin_amdgcn_exp2f(sT[r]);

      // P (C-layout) -> A-frag via cvt_pk + permlane32_swap  [T12]
      uint32 cw0 = cvtpk(sT[0],  sT[1]),  cw1 = cvtpk(sT[2],  sT[3]);
      uint32 cw2 = cvtpk(sT[4],  sT[5]),  cw3 = cvtpk(sT[6],  sT[7]);
      uint32 cw4 = cvtpk(sT[8],  sT[9]),  cw5 = cvtpk(sT[10], sT[11]);
      uint32 cw6 = cvtpk(sT[12], sT[13]), cw7 = cvtpk(sT[14], sT[15]);
      permswap(cw0, cw2); permswap(cw1, cw3);
      permswap(cw4, cw6); permswap(cw5, cw7);
      bf16x8 pa0 = __builtin_bit_cast(bf16x8, u32x4{cw0, cw1, cw2, cw3});
      bf16x8 pa1 = __builtin_bit_cast(bf16x8, u32x4{cw4, cw5, cw6, cw7});

      // V frags: V[k=ksub+koff+hi*8 ..+8][d=l31 / l31+32]
      const int vr0 = l31 * 64, vr1 = (l31 + 32) * 64;
      bf16x8 v00 = *(const bf16x8*)&vt[vr0 + ((ksub + hi * 8)      ^ sxor)];
      bf16x8 v01 = *(const bf16x8*)&vt[vr0 + ((ksub + 16 + hi * 8) ^ sxor)];
      bf16x8 v10 = *(const bf16x8*)&vt[vr1 + ((ksub + hi * 8)      ^ sxor)];
      bf16x8 v11 = *(const bf16x8*)&vt[vr1 + ((ksub + 16 + hi * 8) ^ sxor)];

      rs   = mfma32(pa0, ones, rs);     // rowsum on the MFMA pipe
      rs   = mfma32(pa1, ones, rs);
      acc0 = mfma32(pa0, v00, acc0);
      acc0 = mfma32(pa1, v01, acc0);
      acc1 = mfma32(pa0, v10, acc1);
      acc1 = mfma32(pa1, v11, acc1);
    }
    asm volatile("s_waitcnt vmcnt(0)");
    __syncthreads();
    cur ^= 1;
  }

  // partial row sums: every column of rs identical; lanes 0 and 32 cover all 32 q rows
  if (l31 == 0) {
    float* lsp = Ls + ((size_t)kh * 56 + inst) * 2048 + qbase;
    #pragma unroll
    for (int r = 0; r < 16; ++r) {
      const int qrow = (r & 3) + 8 * (r >> 2) + 4 * hi;
      lsp[qrow] = rs[r];
    }
  }
  // partial O, bf16-packed {d, d+32}: C row q=(r&3)+8*(r>>2)+4*hi
  uint32* op = Op32 + (size_t)kh * (56u * 2048u * 32u)
                    + ((size_t)inst * 2048 + qbase) * 32 + l31;
  #pragma unroll
  for (int r = 0; r < 16; ++r) {
    const int qrow = (r & 3) + 8 * (r >> 2) + 4 * hi;
    op[(size_t)qrow * 32] = cvtpk(acc0[r], acc1[r]);
  }
}

// ---------------- gather + combine split-K + normalize + LayerNorm -> xln ----------------
__global__ __launch_bounds__(256) void ln_gather(
    const uint32* __restrict__ Op32, const float* __restrict__ Ls,
    const float* __restrict__ gamma, const float* __restrict__ beta,
    u16* __restrict__ xln)
{
  const int row = blockIdx.x;            // 0..16383
  const int b = row >> 13, nn = row & 8191;
  const int tid = threadIdx.x;
  const size_t KHOFF = 56u * 2048u * 32u;
  float v[3];
  #pragma unroll
  for (int j = 0; j < 3; ++j) {
    const int e = tid + j * 256;
    const int h = e >> 6, d = e & 63;
    const int grp = h >> 2, hg = h & 3;
    const int p = nn & ((2048 << grp) - 1);
    float val = 0.f;
    if ((p & ((1 << grp) - 1)) == grp) {
      const int seg = nn >> (11 + grp);
      const int instB = (grp == 0) ? 0 : (grp == 1) ? 32 : 48;
      const int inst = instB + ((b * (4 >> grp) + seg) << 2) + hg;
      const int t = (p - grp) >> grp;
      const size_t wbase = ((size_t)inst * 2048 + t) * 32 + (d & 31);
      const uint32 w0 = Op32[wbase];
      const uint32 w1 = Op32[wbase + KHOFF];
      const float o0 = __builtin_bit_cast(float, d < 32 ? (w0 << 16) : (w0 & 0xFFFF0000u));
      const float o1 = __builtin_bit_cast(float, d < 32 ? (w1 << 16) : (w1 & 0xFFFF0000u));
      const float s = Ls[(size_t)inst * 2048 + t] + Ls[(size_t)(56 * 2048) + inst * 2048 + t];
      val = (o0 + o1) * (1.0f / (3.0f * s));
    }
    v[j] = val;
  }
  float s = v[0] + v[1] + v[2];
  float q = v[0]*v[0] + v[1]*v[1] + v[2]*v[2];
  #pragma unroll
  for (int off = 1; off < 64; off <<= 1) { s += __shfl_xor(s, off); q += __shfl_xor(q, off); }
  __shared__ float red[8];
  const int w = tid >> 6, l = tid & 63;
  if (l == 0) { red[w] = s; red[4 + w] = q; }
  __syncthreads();
  s = red[0] + red[1] + red[2] + red[3];
  q = red[4] + red[5] + red[6] + red[7];
  const float mu = s * (1.f / 768.f);
  const float var = q * (1.f / 768.f) - mu * mu;
  const float rs = rsqrtf(var + 1e-5f);
  #pragma unroll
  for (int j = 0; j < 3; ++j) {
    const int e = tid + j * 256;
    xln[(size_t)row * 768 + e] = f2bf((v[j] - mu) * rs * gamma[e] + beta[e]);
  }
}

// ---------------- output projection GEMM (bf16 A, f32 out) ----------------
__global__ __launch_bounds__(256) void out_gemm(
    const u16* __restrict__ Xb, const u16* __restrict__ W,
    const float* __restrict__ bias, float* __restrict__ out)
{
  __shared__ u16 As[128 * LDK];
  __shared__ u16 Bs[128 * LDK];
  const int tid = threadIdx.x;
  const int l = tid & 63, w = tid >> 6;
  const int l15 = l & 15, lh = l >> 4;
  const int wr = w >> 1, wc = w & 1;
  const int row0 = blockIdx.x * 128, col0 = blockIdx.y * 128;
  const int sr = tid >> 1, skc = (tid & 1) * 16;

  const u16* ap = Xb + (size_t)(row0 + sr) * 768 + skc;
  const u16* bp = W + (size_t)(col0 + sr) * 768 + skc;

  f32x4 acc[4][4];
  #pragma unroll
  for (int i = 0; i < 4; ++i)
    #pragma unroll
    for (int j = 0; j < 4; ++j) acc[i][j] = f32x4{0.f, 0.f, 0.f, 0.f};

  i16x8 ra0, ra1, rb0, rb1;
  ra0 = *(const i16x8*)(ap); ra1 = *(const i16x8*)(ap + 8);
  rb0 = *(const i16x8*)(bp); rb1 = *(const i16x8*)(bp + 8);

  for (int ks = 0; ks < 24; ++ks) {
    __syncthreads();
    *(i16x8*)&As[sr * LDK + skc]     = ra0;
    *(i16x8*)&As[sr * LDK + skc + 8] = ra1;
    *(i16x8*)&Bs[sr * LDK + skc]     = rb0;
    *(i16x8*)&Bs[sr * LDK + skc + 8] = rb1;
    __syncthreads();
    if (ks < 23) {
      const u16* ap2 = ap + (ks + 1) * 32;
      const u16* bp2 = bp + (ks + 1) * 32;
      ra0 = *(const i16x8*)(ap2); ra1 = *(const i16x8*)(ap2 + 8);
      rb0 = *(const i16x8*)(bp2); rb1 = *(const i16x8*)(bp2 + 8);
    }
    bf16x8 af[4], bfr[4];
    #pragma unroll
    for (int mi = 0; mi < 4; ++mi)
      af[mi] = *(const bf16x8*)&As[(wr * 64 + mi * 16 + l15) * LDK + lh * 8];
    #pragma unroll
    for (int ni = 0; ni < 4; ++ni)
      bfr[ni] = *(const bf16x8*)&Bs[(wc * 64 + ni * 16 + l15) * LDK + lh * 8];
    #pragma unroll
    for (int mi = 0; mi < 4; ++mi)
      #pragma unroll
      for (int ni = 0; ni < 4; ++ni)
        acc[mi][ni] = mfma16(af[mi], bfr[ni], acc[mi][ni]);
  }

  #pragma unroll
  for (int ni = 0; ni < 4; ++ni) {
    const int e = col0 + wc * 64 + ni * 16 + l15;
    const float bia = bias[e];
    #pragma unroll
    for (int mi = 0; mi < 4; ++mi) {
      #pragma unroll
      for (int r = 0; r < 4; ++r) {
        const int row = row0 + wr * 64 + mi * 16 + lh * 4 + r;
        out[(size_t)row * 768 + e] = acc[mi][ni][r] + bia;
      }
    }
  }
}

extern "C" void kernel_launch(void* const* d_in, const int* in_sizes, int n_in,
                              void* d_out, int out_size, void* d_ws, size_t ws_size,
                              hipStream_t stream) {
  const float* query = (const float*)d_in[0];
  const float* key_  = (const float*)d_in[1];
  const float* value = (const float*)d_in[2];
  const float* Wq = (const float*)d_in[3];
  const float* bq = (const float*)d_in[4];
  const float* Wk = (const float*)d_in[5];
  const float* bk = (const float*)d_in[6];
  const float* Wv = (const float*)d_in[7];
  const float* bv = (const float*)d_in[8];
  const float* Wo = (const float*)d_in[9];
  const float* bo = (const float*)d_in[10];
  const float* lng = (const float*)d_in[11];
  const float* lnb = (const float*)d_in[12];

  char* ws = (char*)d_ws;
  size_t off = 0;
  auto alloc = [&](size_t bytes) { size_t o = off; off += (bytes + 255) & ~(size_t)255; return o; };
  const size_t WB = 768 * 768 * 2;           // bf16 weight bytes
  const size_t GB = (size_t)56 * ISTR * 2;   // gathered bf16 bytes
  u16* wqb = (u16*)(ws + alloc(WB));
  u16* wkb = (u16*)(ws + alloc(WB));
  u16* wvb = (u16*)(ws + alloc(WB));
  u16* wob = (u16*)(ws + alloc(WB));
  u16* Qg  = (u16*)(ws + alloc(GB));
  u16* Kg  = (u16*)(ws + alloc(GB));
  u16* VgT = (u16*)(ws + alloc(GB));
  uint32* Op32 = (uint32*)(ws + alloc((size_t)2 * 56 * 2048 * 32 * 4));
  float* Lsb  = (float*)(ws + alloc((size_t)2 * 56 * 2048 * 4));
  u16* xln = (u16*)(ws + alloc((size_t)16384 * 768 * 2));

  const int n4 = 768 * 768 / 4;
  cvt_w<<<dim3(576), 256, 0, stream>>>(Wq, wqb, n4);
  cvt_w<<<dim3(576), 256, 0, stream>>>(Wk, wkb, n4);
  cvt_w<<<dim3(576), 256, 0, stream>>>(Wv, wvb, n4);
  cvt_w<<<dim3(576), 256, 0, stream>>>(Wo, wob, n4);

  qkv_gemm<<<dim3(128, 6), 256, 0, stream>>>(query, wqb, bq, Qg, QSCALE, 0);
  qkv_gemm<<<dim3(128, 6), 256, 0, stream>>>(key_,  wkb, bk, Kg, 1.0f, 0);
  qkv_gemm<<<dim3(128, 6), 256, 0, stream>>>(value, wvb, bv, VgT, 1.0f, 1);

  dil_attn<<<dim3(1792), 256, 0, stream>>>(Qg, Kg, VgT, Op32, Lsb);
  ln_gather<<<dim3(16384), 256, 0, stream>>>(Op32, Lsb, lng, lnb, xln);
  out_gemm<<<dim3(128, 6), 256, 0, stream>>>(xln, wob, bo, (float*)d_out);
}

// Round 6
// 287.579 us; speedup vs baseline: 2.1030x; 1.0375x over previous
//
#include <hip/hip_runtime.h>
#include <hip/hip_bf16.h>
#include <stdint.h>

typedef unsigned int uint32;
typedef unsigned short u16;
typedef __attribute__((ext_vector_type(4))) float f32x4;
typedef __attribute__((ext_vector_type(16))) float f32x16;
typedef __attribute__((ext_vector_type(8))) __bf16 bf16x8;
typedef __attribute__((ext_vector_type(8))) short i16x8;
typedef __attribute__((ext_vector_type(4))) short i16x4;
typedef __attribute__((ext_vector_type(4))) uint32 u32x4;

#define DEVINL static __device__ __forceinline__

DEVINL u16 f2bf(float f){
  uint32 u = __builtin_bit_cast(uint32, f);
  return (u16)((u + 0x7fffu + ((u >> 16) & 1u)) >> 16);  // RNE
}

DEVINL uint32 cvtpk(float lo, float hi){
  uint32 r;
  asm("v_cvt_pk_bf16_f32 %0, %1, %2" : "=v"(r) : "v"(lo), "v"(hi));
  return r;
}

// vdst.hi32lanes <-> vsrc.lo32lanes
DEVINL void permswap(uint32 &a, uint32 &b){
  asm volatile("s_nop 1\n\tv_permlane32_swap_b32 %0, %1" : "+v"(a), "+v"(b));
}

DEVINL f32x4 mfma16(bf16x8 a, bf16x8 b, f32x4 c){
  return __builtin_amdgcn_mfma_f32_16x16x32_bf16(a, b, c, 0, 0, 0);
}
DEVINL f32x16 mfma32(bf16x8 a, bf16x8 b, f32x16 c){
  return __builtin_amdgcn_mfma_f32_32x32x16_bf16(a, b, c, 0, 0, 0);
}
DEVINL f32x16 zero16(){
  f32x16 z;
  #pragma unroll
  for (int r = 0; r < 16; ++r) z[r] = 0.f;
  return z;
}

// async global->LDS, 16B per lane; LDS dest is wave-uniform base + lane*16
DEVINL void gload16(const u16* g, u16* l){
  __builtin_amdgcn_global_load_lds(
      (const __attribute__((address_space(1))) uint32*)g,
      (__attribute__((address_space(3))) uint32*)l, 16, 0, 0);
}

static constexpr size_t ISTR = 2048 * 64;   // elems per attention instance
static constexpr float QSCALE = 0.18033688011112042f;  // log2(e)/8 folded into Q

// ---------------- weight f32 -> bf16 (all four in one dispatch) ----------------
__global__ void cvt_w4(const float* __restrict__ s0, const float* __restrict__ s1,
                       const float* __restrict__ s2, const float* __restrict__ s3,
                       u16* __restrict__ d0, u16* __restrict__ d1,
                       u16* __restrict__ d2, u16* __restrict__ d3, int n4){
  const int wsel = blockIdx.y;
  const float* src = wsel == 0 ? s0 : wsel == 1 ? s1 : wsel == 2 ? s2 : s3;
  u16* dst = wsel == 0 ? d0 : wsel == 1 ? d1 : wsel == 2 ? d2 : d3;
  int i = blockIdx.x * 256 + threadIdx.x;
  if (i < n4){
    f32x4 v = *(const f32x4*)(src + (size_t)i * 4);
    u16 o[4];
    #pragma unroll
    for (int j = 0; j < 4; ++j) o[j] = f2bf(v[j]);
    *(i16x4*)(dst + (size_t)i * 4) = *(const i16x4*)o;
  }
}

// ---------------- fused QKV projection GEMM ----------------
// grid (128, 18): y/6 = section (0:Q, 1:K, 2:V), (y%6)*128 = col tile.
// A (f32 input) register-staged + cvtpk -> LDS; B (bf16 weight) via global_load_lds.
// Double-buffered, 1 barrier per K-step. Epilogue scatters to gathered layout.
__global__ __launch_bounds__(256) void qkv_fused(
    const float* __restrict__ X0, const float* __restrict__ X1, const float* __restrict__ X2,
    const u16* __restrict__ W0, const u16* __restrict__ W1, const u16* __restrict__ W2,
    const float* __restrict__ b0, const float* __restrict__ b1, const float* __restrict__ b2,
    u16* __restrict__ Y0, u16* __restrict__ Y1, u16* __restrict__ Y2)
{
  __shared__ u16 As[2][128 * 32];
  __shared__ u16 Bs[2][128 * 32];
  const int tid = threadIdx.x;
  const int l = tid & 63, w = tid >> 6;
  const int l15 = l & 15, lh = l >> 4;
  const int wr = w >> 1, wc = w & 1;
  const int yb = blockIdx.y;
  const int sect = yb / 6;
  const int row0 = blockIdx.x * 128, col0 = (yb % 6) * 128;

  const float* X   = sect == 0 ? X0 : sect == 1 ? X1 : X2;
  const u16*   W   = sect == 0 ? W0 : sect == 1 ? W1 : W2;
  const float* bia_p = sect == 0 ? b0 : sect == 1 ? b1 : b2;
  u16*         Yg  = sect == 0 ? Y0 : sect == 1 ? Y1 : Y2;
  const float scale = sect == 0 ? QSCALE : 1.0f;
  const int tmode = (sect == 2) ? 1 : 0;

  // B staging via gload16: lane covers row gr=l>>2 within 16-row group, 8-elem chunk gc
  const int gr = l >> 2, gc = (l & 3) * 8;
  const u16* wsrc0 = W + (size_t)(col0 + w * 32 + gr) * 768 + gc;

  // A staging: thread t loads 16 f32 of row sr, writes 16 bf16
  const int sr = tid >> 1, sc = (tid & 1) * 16;
  const float* asrc = X + (size_t)(row0 + sr) * 768 + sc;

  f32x4 acc[4][4];
  #pragma unroll
  for (int i = 0; i < 4; ++i)
    #pragma unroll
    for (int j = 0; j < 4; ++j) acc[i][j] = f32x4{0.f, 0.f, 0.f, 0.f};

  auto STAGE_B = [&](int buf, int ks){
    const u16* ws = wsrc0 + ks * 32;
    gload16(ws,            &Bs[buf][(w * 32) * 32]);
    gload16(ws + 16 * 768, &Bs[buf][(w * 32 + 16) * 32]);
  };
  auto WRITE_A = [&](int buf, f32x4 ra0, f32x4 ra1, f32x4 ra2, f32x4 ra3){
    u32x4 w0 = { cvtpk(ra0[0], ra0[1]), cvtpk(ra0[2], ra0[3]),
                 cvtpk(ra1[0], ra1[1]), cvtpk(ra1[2], ra1[3]) };
    u32x4 w1 = { cvtpk(ra2[0], ra2[1]), cvtpk(ra2[2], ra2[3]),
                 cvtpk(ra3[0], ra3[1]), cvtpk(ra3[2], ra3[3]) };
    *(i16x8*)&As[buf][sr * 32 + sc]     = __builtin_bit_cast(i16x8, w0);
    *(i16x8*)&As[buf][sr * 32 + sc + 8] = __builtin_bit_cast(i16x8, w1);
  };

  // prologue: stage step 0
  {
    STAGE_B(0, 0);
    f32x4 ra0 = *(const f32x4*)(asrc);
    f32x4 ra1 = *(const f32x4*)(asrc + 4);
    f32x4 ra2 = *(const f32x4*)(asrc + 8);
    f32x4 ra3 = *(const f32x4*)(asrc + 12);
    WRITE_A(0, ra0, ra1, ra2, ra3);
  }
  asm volatile("s_waitcnt vmcnt(0)");
  __syncthreads();

  int cur = 0;
  for (int ks = 0; ks < 24; ++ks) {
    const int nxt = cur ^ 1;
    f32x4 ra0, ra1, ra2, ra3;
    const bool has = ks < 23;
    if (has) {
      STAGE_B(nxt, ks + 1);
      const float* ap = asrc + (ks + 1) * 32;
      ra0 = *(const f32x4*)(ap);      ra1 = *(const f32x4*)(ap + 4);
      ra2 = *(const f32x4*)(ap + 8);  ra3 = *(const f32x4*)(ap + 12);
    }
    bf16x8 af[4], bfr[4];
    #pragma unroll
    for (int mi = 0; mi < 4; ++mi)
      af[mi] = *(const bf16x8*)&As[cur][(wr * 64 + mi * 16 + l15) * 32 + lh * 8];
    #pragma unroll
    for (int ni = 0; ni < 4; ++ni)
      bfr[ni] = *(const bf16x8*)&Bs[cur][(wc * 64 + ni * 16 + l15) * 32 + lh * 8];
    #pragma unroll
    for (int mi = 0; mi < 4; ++mi)
      #pragma unroll
      for (int ni = 0; ni < 4; ++ni)
        acc[mi][ni] = mfma16(af[mi], bfr[ni], acc[mi][ni]);
    if (has) WRITE_A(nxt, ra0, ra1, ra2, ra3);
    asm volatile("s_waitcnt vmcnt(0)");
    __syncthreads();
    cur = nxt;
  }

  // scatter epilogue: C layout col=lane&15, row=(lane>>4)*4+reg  [m89]
  #pragma unroll
  for (int ni = 0; ni < 4; ++ni) {
    const int e = col0 + wc * 64 + ni * 16 + l15;
    const int h = e >> 6, d = e & 63;
    const int grp = h >> 2, hg = h & 3;
    const int instB = (grp == 0) ? 0 : (grp == 1) ? 32 : 48;
    const float bia = bia_p[e];
    #pragma unroll
    for (int mi = 0; mi < 4; ++mi) {
      #pragma unroll
      for (int r = 0; r < 4; ++r) {
        const int row = row0 + wr * 64 + mi * 16 + lh * 4 + r;
        const int b = row >> 13, nn = row & 8191;
        const int p = nn & ((2048 << grp) - 1);
        if ((p & ((1 << grp) - 1)) != grp) continue;   // off dilation grid
        const int seg = nn >> (11 + grp);
        const int t = (p - grp) >> grp;
        const int inst = instB + ((b * (4 >> grp) + seg) << 2) + hg;
        const u16 val = f2bf((acc[mi][ni][r] + bia) * scale);
        if (tmode == 0) Yg[(size_t)inst * ISTR + (size_t)t * 64 + d] = val;
        else            Yg[(size_t)inst * ISTR + (size_t)d * 2048 + t] = val;
      }
    }
  }
}

// ---------------- dilated flash attention: 4 waves, LDS-staged K/V, split-K 2 ----------------
__global__ __launch_bounds__(256) void dil_attn(
    const u16* __restrict__ Qg, const u16* __restrict__ Kg,
    const u16* __restrict__ VgT, uint32* __restrict__ Op32, float* __restrict__ Ls)
{
  __shared__ u16 Kb[2][64 * 64];
  __shared__ u16 Vb[2][64 * 64];
  const int tid = threadIdx.x;
  const int w = tid >> 6, l = tid & 63;
  const int l31 = l & 31, hi = l >> 5;
  const int id = blockIdx.x;
  const int nid = (id & 7) * 224 + (id >> 3);
  const int inst = nid >> 5, rem = nid & 31;
  const int qb = rem >> 1, kh = rem & 1;
  const size_t ibase = (size_t)inst * ISTR;
  const int qbase = qb * 128 + w * 32;
  const int k0base = kh * 1024;

  const u16* qlane = Qg + ibase + (size_t)(qbase + l31) * 64 + hi * 8;
  const bf16x8 qf0 = *(const bf16x8*)(qlane);
  const bf16x8 qf1 = *(const bf16x8*)(qlane + 16);
  const bf16x8 qf2 = *(const bf16x8*)(qlane + 32);
  const bf16x8 qf3 = *(const bf16x8*)(qlane + 48);

  const int srow = l >> 3;
  const int scol = ((l & 7) ^ (srow & 7)) << 3;
  const u16* kgs = Kg  + ibase + (size_t)srow * 64 + scol;
  const u16* vgs = VgT + ibase + (size_t)srow * 2048 + scol;

  f32x16 acc0 = zero16(), acc1 = zero16(), rs = zero16();
  const int sxor = (l31 & 7) << 3;
  const bf16x8 ones = __builtin_bit_cast(bf16x8,
      u32x4{0x3F803F80u, 0x3F803F80u, 0x3F803F80u, 0x3F803F80u});

  auto STAGE = [&](int buf, int k0){
    #pragma unroll
    for (int q = 0; q < 2; ++q){
      const int rb = w * 16 + q * 8;
      gload16(kgs + (size_t)(k0 + rb) * 64, &Kb[buf][rb * 64]);
      gload16(vgs + (size_t)rb * 2048 + k0, &Vb[buf][rb * 64]);
    }
  };

  STAGE(0, k0base);
  asm volatile("s_waitcnt vmcnt(0)");
  __syncthreads();

  int cur = 0;
  for (int step = 0; step < 16; ++step) {
    if (step < 15) STAGE(cur ^ 1, k0base + ((step + 1) << 6));
    const u16* kt = &Kb[cur][0];
    const u16* vt = &Vb[cur][0];
    #pragma unroll
    for (int s = 0; s < 2; ++s) {
      const int ksub = s * 32;
      const int krow = (ksub + l31) * 64;
      bf16x8 kc0 = *(const bf16x8*)&kt[krow + ((hi * 8)      ^ sxor)];
      bf16x8 kc1 = *(const bf16x8*)&kt[krow + ((16 + hi * 8) ^ sxor)];
      bf16x8 kc2 = *(const bf16x8*)&kt[krow + ((32 + hi * 8) ^ sxor)];
      bf16x8 kc3 = *(const bf16x8*)&kt[krow + ((48 + hi * 8) ^ sxor)];

      f32x16 sT = zero16();
      sT = mfma32(kc0, qf0, sT);
      sT = mfma32(kc1, qf1, sT);
      sT = mfma32(kc2, qf2, sT);
      sT = mfma32(kc3, qf3, sT);

      #pragma unroll
      for (int r = 0; r < 16; ++r) sT[r] = __builtin_amdgcn_exp2f(sT[r]);

      uint32 cw0 = cvtpk(sT[0],  sT[1]),  cw1 = cvtpk(sT[2],  sT[3]);
      uint32 cw2 = cvtpk(sT[4],  sT[5]),  cw3 = cvtpk(sT[6],  sT[7]);
      uint32 cw4 = cvtpk(sT[8],  sT[9]),  cw5 = cvtpk(sT[10], sT[11]);
      uint32 cw6 = cvtpk(sT[12], sT[13]), cw7 = cvtpk(sT[14], sT[15]);
      permswap(cw0, cw2); permswap(cw1, cw3);
      permswap(cw4, cw6); permswap(cw5, cw7);
      bf16x8 pa0 = __builtin_bit_cast(bf16x8, u32x4{cw0, cw1, cw2, cw3});
      bf16x8 pa1 = __builtin_bit_cast(bf16x8, u32x4{cw4, cw5, cw6, cw7});

      const int vr0 = l31 * 64, vr1 = (l31 + 32) * 64;
      bf16x8 v00 = *(const bf16x8*)&vt[vr0 + ((ksub + hi * 8)      ^ sxor)];
      bf16x8 v01 = *(const bf16x8*)&vt[vr0 + ((ksub + 16 + hi * 8) ^ sxor)];
      bf16x8 v10 = *(const bf16x8*)&vt[vr1 + ((ksub + hi * 8)      ^ sxor)];
      bf16x8 v11 = *(const bf16x8*)&vt[vr1 + ((ksub + 16 + hi * 8) ^ sxor)];

      rs   = mfma32(pa0, ones, rs);
      rs   = mfma32(pa1, ones, rs);
      acc0 = mfma32(pa0, v00, acc0);
      acc0 = mfma32(pa1, v01, acc0);
      acc1 = mfma32(pa0, v10, acc1);
      acc1 = mfma32(pa1, v11, acc1);
    }
    asm volatile("s_waitcnt vmcnt(0)");
    __syncthreads();
    cur ^= 1;
  }

  if (l31 == 0) {
    float* lsp = Ls + ((size_t)kh * 56 + inst) * 2048 + qbase;
    #pragma unroll
    for (int r = 0; r < 16; ++r) {
      const int qrow = (r & 3) + 8 * (r >> 2) + 4 * hi;
      lsp[qrow] = rs[r];
    }
  }
  uint32* op = Op32 + (size_t)kh * (56u * 2048u * 32u)
                    + ((size_t)inst * 2048 + qbase) * 32 + l31;
  #pragma unroll
  for (int r = 0; r < 16; ++r) {
    const int qrow = (r & 3) + 8 * (r >> 2) + 4 * hi;
    op[(size_t)qrow * 32] = cvtpk(acc0[r], acc1[r]);
  }
}

// ---------------- gather + combine split-K + normalize + LayerNorm -> xln ----------------
__global__ __launch_bounds__(256) void ln_gather(
    const uint32* __restrict__ Op32, const float* __restrict__ Ls,
    const float* __restrict__ gamma, const float* __restrict__ beta,
    u16* __restrict__ xln)
{
  const int row = blockIdx.x;            // 0..16383
  const int b = row >> 13, nn = row & 8191;
  const int tid = threadIdx.x;
  const size_t KHOFF = 56u * 2048u * 32u;
  float v[3];
  #pragma unroll
  for (int j = 0; j < 3; ++j) {
    const int e = tid + j * 256;
    const int h = e >> 6, d = e & 63;
    const int grp = h >> 2, hg = h & 3;
    const int p = nn & ((2048 << grp) - 1);
    float val = 0.f;
    if ((p & ((1 << grp) - 1)) == grp) {
      const int seg = nn >> (11 + grp);
      const int instB = (grp == 0) ? 0 : (grp == 1) ? 32 : 48;
      const int inst = instB + ((b * (4 >> grp) + seg) << 2) + hg;
      const int t = (p - grp) >> grp;
      const size_t wbase = ((size_t)inst * 2048 + t) * 32 + (d & 31);
      const uint32 w0 = Op32[wbase];
      const uint32 w1 = Op32[wbase + KHOFF];
      const float o0 = __builtin_bit_cast(float, d < 32 ? (w0 << 16) : (w0 & 0xFFFF0000u));
      const float o1 = __builtin_bit_cast(float, d < 32 ? (w1 << 16) : (w1 & 0xFFFF0000u));
      const float s = Ls[(size_t)inst * 2048 + t] + Ls[(size_t)(56 * 2048) + inst * 2048 + t];
      val = (o0 + o1) * (1.0f / (3.0f * s));
    }
    v[j] = val;
  }
  float s = v[0] + v[1] + v[2];
  float q = v[0]*v[0] + v[1]*v[1] + v[2]*v[2];
  #pragma unroll
  for (int off = 1; off < 64; off <<= 1) { s += __shfl_xor(s, off); q += __shfl_xor(q, off); }
  __shared__ float red[8];
  const int w = tid >> 6, l = tid & 63;
  if (l == 0) { red[w] = s; red[4 + w] = q; }
  __syncthreads();
  s = red[0] + red[1] + red[2] + red[3];
  q = red[4] + red[5] + red[6] + red[7];
  const float mu = s * (1.f / 768.f);
  const float var = q * (1.f / 768.f) - mu * mu;
  const float rs = rsqrtf(var + 1e-5f);
  #pragma unroll
  for (int j = 0; j < 3; ++j) {
    const int e = tid + j * 256;
    xln[(size_t)row * 768 + e] = f2bf((v[j] - mu) * rs * gamma[e] + beta[e]);
  }
}

// ---------------- output projection GEMM (bf16 A and B via global_load_lds) ----------------
__global__ __launch_bounds__(256) void out_gemm(
    const u16* __restrict__ Xb, const u16* __restrict__ W,
    const float* __restrict__ bias, float* __restrict__ out)
{
  __shared__ u16 As[2][128 * 32];
  __shared__ u16 Bs[2][128 * 32];
  const int tid = threadIdx.x;
  const int l = tid & 63, w = tid >> 6;
  const int l15 = l & 15, lh = l >> 4;
  const int wr = w >> 1, wc = w & 1;
  const int row0 = blockIdx.x * 128, col0 = blockIdx.y * 128;

  const int gr = l >> 2, gc = (l & 3) * 8;
  const u16* asrc0 = Xb + (size_t)(row0 + w * 32 + gr) * 768 + gc;
  const u16* wsrc0 = W  + (size_t)(col0 + w * 32 + gr) * 768 + gc;

  f32x4 acc[4][4];
  #pragma unroll
  for (int i = 0; i < 4; ++i)
    #pragma unroll
    for (int j = 0; j < 4; ++j) acc[i][j] = f32x4{0.f, 0.f, 0.f, 0.f};

  auto STAGE = [&](int buf, int ks){
    const u16* as = asrc0 + ks * 32;
    const u16* ws = wsrc0 + ks * 32;
    gload16(as,            &As[buf][(w * 32) * 32]);
    gload16(as + 16 * 768, &As[buf][(w * 32 + 16) * 32]);
    gload16(ws,            &Bs[buf][(w * 32) * 32]);
    gload16(ws + 16 * 768, &Bs[buf][(w * 32 + 16) * 32]);
  };

  STAGE(0, 0);
  asm volatile("s_waitcnt vmcnt(0)");
  __syncthreads();

  int cur = 0;
  for (int ks = 0; ks < 24; ++ks) {
    const int nxt = cur ^ 1;
    if (ks < 23) STAGE(nxt, ks + 1);
    bf16x8 af[4], bfr[4];
    #pragma unroll
    for (int mi = 0; mi < 4; ++mi)
      af[mi] = *(const bf16x8*)&As[cur][(wr * 64 + mi * 16 + l15) * 32 + lh * 8];
    #pragma unroll
    for (int ni = 0; ni < 4; ++ni)
      bfr[ni] = *(const bf16x8*)&Bs[cur][(wc * 64 + ni * 16 + l15) * 32 + lh * 8];
    #pragma unroll
    for (int mi = 0; mi < 4; ++mi)
      #pragma unroll
      for (int ni = 0; ni < 4; ++ni)
        acc[mi][ni] = mfma16(af[mi], bfr[ni], acc[mi][ni]);
    asm volatile("s_waitcnt vmcnt(0)");
    __syncthreads();
    cur = nxt;
  }

  #pragma unroll
  for (int ni = 0; ni < 4; ++ni) {
    const int e = col0 + wc * 64 + ni * 16 + l15;
    const float bia = bias[e];
    #pragma unroll
    for (int mi = 0; mi < 4; ++mi) {
      #pragma unroll
      for (int r = 0; r < 4; ++r) {
        const int row = row0 + wr * 64 + mi * 16 + lh * 4 + r;
        out[(size_t)row * 768 + e] = acc[mi][ni][r] + bia;
      }
    }
  }
}

extern "C" void kernel_launch(void* const* d_in, const int* in_sizes, int n_in,
                              void* d_out, int out_size, void* d_ws, size_t ws_size,
                              hipStream_t stream) {
  const float* query = (const float*)d_in[0];
  const float* key_  = (const float*)d_in[1];
  const float* value = (const float*)d_in[2];
  const float* Wq = (const float*)d_in[3];
  const float* bq = (const float*)d_in[4];
  const float* Wk = (const float*)d_in[5];
  const float* bk = (const float*)d_in[6];
  const float* Wv = (const float*)d_in[7];
  const float* bv = (const float*)d_in[8];
  const float* Wo = (const float*)d_in[9];
  const float* bo = (const float*)d_in[10];
  const float* lng = (const float*)d_in[11];
  const float* lnb = (const float*)d_in[12];

  char* ws = (char*)d_ws;
  size_t off = 0;
  auto alloc = [&](size_t bytes) { size_t o = off; off += (bytes + 255) & ~(size_t)255; return o; };
  const size_t WB = 768 * 768 * 2;           // bf16 weight bytes
  const size_t GB = (size_t)56 * ISTR * 2;   // gathered bf16 bytes
  u16* wqb = (u16*)(ws + alloc(WB));
  u16* wkb = (u16*)(ws + alloc(WB));
  u16* wvb = (u16*)(ws + alloc(WB));
  u16* wob = (u16*)(ws + alloc(WB));
  u16* Qg  = (u16*)(ws + alloc(GB));
  u16* Kg  = (u16*)(ws + alloc(GB));
  u16* VgT = (u16*)(ws + alloc(GB));
  uint32* Op32 = (uint32*)(ws + alloc((size_t)2 * 56 * 2048 * 32 * 4));
  float* Lsb  = (float*)(ws + alloc((size_t)2 * 56 * 2048 * 4));
  u16* xln = (u16*)(ws + alloc((size_t)16384 * 768 * 2));

  const int n4 = 768 * 768 / 4;
  cvt_w4<<<dim3(576, 4), 256, 0, stream>>>(Wq, Wk, Wv, Wo, wqb, wkb, wvb, wob, n4);

  qkv_fused<<<dim3(128, 18), 256, 0, stream>>>(
      query, key_, value, wqb, wkb, wvb, bq, bk, bv, Qg, Kg, VgT);

  dil_attn<<<dim3(1792), 256, 0, stream>>>(Qg, Kg, VgT, Op32, Lsb);
  ln_gather<<<dim3(16384), 256, 0, stream>>>(Op32, Lsb, lng, lnb, xln);
  out_gemm<<<dim3(128, 6), 256, 0, stream>>>(xln, wob, bo, (float*)d_out);
}

// Round 7
// 287.310 us; speedup vs baseline: 2.1049x; 1.0009x over previous
//
#include <hip/hip_runtime.h>
#include <hip/hip_bf16.h>
#include <stdint.h>

typedef unsigned int uint32;
typedef unsigned short u16;
typedef __attribute__((ext_vector_type(4))) float f32x4;
typedef __attribute__((ext_vector_type(16))) float f32x16;
typedef __attribute__((ext_vector_type(8))) __bf16 bf16x8;
typedef __attribute__((ext_vector_type(8))) short i16x8;
typedef __attribute__((ext_vector_type(4))) short i16x4;
typedef __attribute__((ext_vector_type(4))) uint32 u32x4;

#define DEVINL static __device__ __forceinline__

DEVINL u16 f2bf(float f){
  uint32 u = __builtin_bit_cast(uint32, f);
  return (u16)((u + 0x7fffu + ((u >> 16) & 1u)) >> 16);  // RNE
}

DEVINL uint32 cvtpk(float lo, float hi){
  uint32 r;
  asm("v_cvt_pk_bf16_f32 %0, %1, %2" : "=v"(r) : "v"(lo), "v"(hi));
  return r;
}

// vdst.hi32lanes <-> vsrc.lo32lanes
DEVINL void permswap(uint32 &a, uint32 &b){
  asm volatile("s_nop 1\n\tv_permlane32_swap_b32 %0, %1" : "+v"(a), "+v"(b));
}

DEVINL f32x4 mfma16(bf16x8 a, bf16x8 b, f32x4 c){
  return __builtin_amdgcn_mfma_f32_16x16x32_bf16(a, b, c, 0, 0, 0);
}
DEVINL f32x16 mfma32(bf16x8 a, bf16x8 b, f32x16 c){
  return __builtin_amdgcn_mfma_f32_32x32x16_bf16(a, b, c, 0, 0, 0);
}
DEVINL f32x16 zero16(){
  f32x16 z;
  #pragma unroll
  for (int r = 0; r < 16; ++r) z[r] = 0.f;
  return z;
}

// async global->LDS, 16B per lane; LDS dest is wave-uniform base + lane*16
DEVINL void gload16(const u16* g, u16* l){
  __builtin_amdgcn_global_load_lds(
      (const __attribute__((address_space(1))) uint32*)g,
      (__attribute__((address_space(3))) uint32*)l, 16, 0, 0);
}

static constexpr size_t ISTR = 2048 * 64;   // elems per attention instance
static constexpr float QSCALE = 0.18033688011112042f;  // log2(e)/8 folded into Q
static constexpr int LDA = 40;              // padded A-tile stride (VALU-written)

// ---------------- weight f32 -> bf16 (all four in one dispatch) ----------------
__global__ void cvt_w4(const float* __restrict__ s0, const float* __restrict__ s1,
                       const float* __restrict__ s2, const float* __restrict__ s3,
                       u16* __restrict__ d0, u16* __restrict__ d1,
                       u16* __restrict__ d2, u16* __restrict__ d3, int n4){
  const int wsel = blockIdx.y;
  const float* src = wsel == 0 ? s0 : wsel == 1 ? s1 : wsel == 2 ? s2 : s3;
  u16* dst = wsel == 0 ? d0 : wsel == 1 ? d1 : wsel == 2 ? d2 : d3;
  int i = blockIdx.x * 256 + threadIdx.x;
  if (i < n4){
    f32x4 v = *(const f32x4*)(src + (size_t)i * 4);
    u16 o[4];
    #pragma unroll
    for (int j = 0; j < 4; ++j) o[j] = f2bf(v[j]);
    *(i16x4*)(dst + (size_t)i * 4) = *(const i16x4*)o;
  }
}

// ---------------- fused QKV projection GEMM ----------------
// grid (128, 18): y/6 = section (0:Q, 1:K, 2:V), (y%6)*128 = col tile.
// A (f32 input) register-staged + cvtpk -> LDS (padded stride LDA=40, conflict-free);
// B (bf16 weight) via global_load_lds with chunk-XOR swizzle (src-preswizzled + XOR read).
__global__ __launch_bounds__(256) void qkv_fused(
    const float* __restrict__ X0, const float* __restrict__ X1, const float* __restrict__ X2,
    const u16* __restrict__ W0, const u16* __restrict__ W1, const u16* __restrict__ W2,
    const float* __restrict__ b0, const float* __restrict__ b1, const float* __restrict__ b2,
    u16* __restrict__ Y0, u16* __restrict__ Y1, u16* __restrict__ Y2)
{
  __shared__ u16 As[2][128 * LDA];
  __shared__ u16 Bs[2][128 * 32];
  const int tid = threadIdx.x;
  const int l = tid & 63, w = tid >> 6;
  const int l15 = l & 15, lh = l >> 4;
  const int wr = w >> 1, wc = w & 1;
  const int yb = blockIdx.y;
  const int sect = yb / 6;
  const int row0 = blockIdx.x * 128, col0 = (yb % 6) * 128;

  const float* X   = sect == 0 ? X0 : sect == 1 ? X1 : X2;
  const u16*   W   = sect == 0 ? W0 : sect == 1 ? W1 : W2;
  const float* bia_p = sect == 0 ? b0 : sect == 1 ? b1 : b2;
  u16*         Yg  = sect == 0 ? Y0 : sect == 1 ? Y1 : Y2;
  const float scale = sect == 0 ? QSCALE : 1.0f;
  const int tmode = (sect == 2) ? 1 : 0;

  // B staging: lane covers row gr = l>>2 (in 16-row group); source chunk pre-XORed so
  // LDS chunk c holds global chunk c ^ ((row>>1)&3)   [T2 / m173 both-sides swizzle]
  const int gr = l >> 2;
  const int gcx = ((l & 3) ^ ((gr >> 1) & 3)) * 8;
  const u16* wsrc0 = W + (size_t)(col0 + w * 32 + gr) * 768 + gcx;

  // A staging: thread t loads 16 f32 of row sr, writes 16 bf16 into padded tile
  const int sr = tid >> 1, sc = (tid & 1) * 16;
  const float* asrc = X + (size_t)(row0 + sr) * 768 + sc;

  f32x4 acc[4][4];
  #pragma unroll
  for (int i = 0; i < 4; ++i)
    #pragma unroll
    for (int j = 0; j < 4; ++j) acc[i][j] = f32x4{0.f, 0.f, 0.f, 0.f};

  auto STAGE_B = [&](int buf, int ks){
    const u16* ws = wsrc0 + ks * 32;
    gload16(ws,            &Bs[buf][(w * 32) * 32]);
    gload16(ws + 16 * 768, &Bs[buf][(w * 32 + 16) * 32]);
  };
  auto WRITE_A = [&](int buf, f32x4 ra0, f32x4 ra1, f32x4 ra2, f32x4 ra3){
    u32x4 w0 = { cvtpk(ra0[0], ra0[1]), cvtpk(ra0[2], ra0[3]),
                 cvtpk(ra1[0], ra1[1]), cvtpk(ra1[2], ra1[3]) };
    u32x4 w1 = { cvtpk(ra2[0], ra2[1]), cvtpk(ra2[2], ra2[3]),
                 cvtpk(ra3[0], ra3[1]), cvtpk(ra3[2], ra3[3]) };
    *(i16x8*)&As[buf][sr * LDA + sc]     = __builtin_bit_cast(i16x8, w0);
    *(i16x8*)&As[buf][sr * LDA + sc + 8] = __builtin_bit_cast(i16x8, w1);
  };

  // prologue: stage step 0
  {
    STAGE_B(0, 0);
    f32x4 ra0 = *(const f32x4*)(asrc);
    f32x4 ra1 = *(const f32x4*)(asrc + 4);
    f32x4 ra2 = *(const f32x4*)(asrc + 8);
    f32x4 ra3 = *(const f32x4*)(asrc + 12);
    WRITE_A(0, ra0, ra1, ra2, ra3);
  }
  asm volatile("s_waitcnt vmcnt(0)");
  __syncthreads();

  const int bxor = ((l15 >> 1) & 3) * 8;   // read-side XOR for B chunks
  int cur = 0;
  for (int ks = 0; ks < 24; ++ks) {
    const int nxt = cur ^ 1;
    f32x4 ra0, ra1, ra2, ra3;
    const bool has = ks < 23;
    if (has) {
      STAGE_B(nxt, ks + 1);
      const float* ap = asrc + (ks + 1) * 32;
      ra0 = *(const f32x4*)(ap);      ra1 = *(const f32x4*)(ap + 4);
      ra2 = *(const f32x4*)(ap + 8);  ra3 = *(const f32x4*)(ap + 12);
    }
    bf16x8 af[4], bfr[4];
    #pragma unroll
    for (int mi = 0; mi < 4; ++mi)
      af[mi] = *(const bf16x8*)&As[cur][(wr * 64 + mi * 16 + l15) * LDA + lh * 8];
    #pragma unroll
    for (int ni = 0; ni < 4; ++ni)
      bfr[ni] = *(const bf16x8*)&Bs[cur][(wc * 64 + ni * 16 + l15) * 32 + ((lh * 8) ^ bxor)];
    #pragma unroll
    for (int mi = 0; mi < 4; ++mi)
      #pragma unroll
      for (int ni = 0; ni < 4; ++ni)
        acc[mi][ni] = mfma16(af[mi], bfr[ni], acc[mi][ni]);
    if (has) WRITE_A(nxt, ra0, ra1, ra2, ra3);
    asm volatile("s_waitcnt vmcnt(0)");
    __syncthreads();
    cur = nxt;
  }

  // scatter epilogue: C layout col=lane&15, row=(lane>>4)*4+reg  [m89]
  #pragma unroll
  for (int ni = 0; ni < 4; ++ni) {
    const int e = col0 + wc * 64 + ni * 16 + l15;
    const int h = e >> 6, d = e & 63;
    const int grp = h >> 2, hg = h & 3;
    const int instB = (grp == 0) ? 0 : (grp == 1) ? 32 : 48;
    const float bia = bia_p[e];
    #pragma unroll
    for (int mi = 0; mi < 4; ++mi) {
      #pragma unroll
      for (int r = 0; r < 4; ++r) {
        const int row = row0 + wr * 64 + mi * 16 + lh * 4 + r;
        const int b = row >> 13, nn = row & 8191;
        const int p = nn & ((2048 << grp) - 1);
        if ((p & ((1 << grp) - 1)) != grp) continue;   // off dilation grid
        const int seg = nn >> (11 + grp);
        const int t = (p - grp) >> grp;
        const int inst = instB + ((b * (4 >> grp) + seg) << 2) + hg;
        const u16 val = f2bf((acc[mi][ni][r] + bia) * scale);
        if (tmode == 0) Yg[(size_t)inst * ISTR + (size_t)t * 64 + d] = val;
        else            Yg[(size_t)inst * ISTR + (size_t)d * 2048 + t] = val;
      }
    }
  }
}

// ---------------- dilated flash attention: 4 waves, LDS-staged K/V, split-K 2 ----------------
__global__ __launch_bounds__(256) void dil_attn(
    const u16* __restrict__ Qg, const u16* __restrict__ Kg,
    const u16* __restrict__ VgT, uint32* __restrict__ Op32, float* __restrict__ Ls)
{
  __shared__ u16 Kb[2][64 * 64];
  __shared__ u16 Vb[2][64 * 64];
  const int tid = threadIdx.x;
  const int w = tid >> 6, l = tid & 63;
  const int l31 = l & 31, hi = l >> 5;
  const int id = blockIdx.x;
  const int nid = (id & 7) * 224 + (id >> 3);
  const int inst = nid >> 5, rem = nid & 31;
  const int qb = rem >> 1, kh = rem & 1;
  const size_t ibase = (size_t)inst * ISTR;
  const int qbase = qb * 128 + w * 32;
  const int k0base = kh * 1024;

  const u16* qlane = Qg + ibase + (size_t)(qbase + l31) * 64 + hi * 8;
  const bf16x8 qf0 = *(const bf16x8*)(qlane);
  const bf16x8 qf1 = *(const bf16x8*)(qlane + 16);
  const bf16x8 qf2 = *(const bf16x8*)(qlane + 32);
  const bf16x8 qf3 = *(const bf16x8*)(qlane + 48);

  const int srow = l >> 3;
  const int scol = ((l & 7) ^ (srow & 7)) << 3;
  const u16* kgs = Kg  + ibase + (size_t)srow * 64 + scol;
  const u16* vgs = VgT + ibase + (size_t)srow * 2048 + scol;

  f32x16 acc0 = zero16(), acc1 = zero16(), rs = zero16();
  const int sxor = (l31 & 7) << 3;
  const bf16x8 ones = __builtin_bit_cast(bf16x8,
      u32x4{0x3F803F80u, 0x3F803F80u, 0x3F803F80u, 0x3F803F80u});

  auto STAGE = [&](int buf, int k0){
    #pragma unroll
    for (int q = 0; q < 2; ++q){
      const int rb = w * 16 + q * 8;
      gload16(kgs + (size_t)(k0 + rb) * 64, &Kb[buf][rb * 64]);
      gload16(vgs + (size_t)rb * 2048 + k0, &Vb[buf][rb * 64]);
    }
  };

  STAGE(0, k0base);
  asm volatile("s_waitcnt vmcnt(0)");
  __syncthreads();

  int cur = 0;
  for (int step = 0; step < 16; ++step) {
    if (step < 15) STAGE(cur ^ 1, k0base + ((step + 1) << 6));
    const u16* kt = &Kb[cur][0];
    const u16* vt = &Vb[cur][0];
    #pragma unroll
    for (int s = 0; s < 2; ++s) {
      const int ksub = s * 32;
      const int krow = (ksub + l31) * 64;
      bf16x8 kc0 = *(const bf16x8*)&kt[krow + ((hi * 8)      ^ sxor)];
      bf16x8 kc1 = *(const bf16x8*)&kt[krow + ((16 + hi * 8) ^ sxor)];
      bf16x8 kc2 = *(const bf16x8*)&kt[krow + ((32 + hi * 8) ^ sxor)];
      bf16x8 kc3 = *(const bf16x8*)&kt[krow + ((48 + hi * 8) ^ sxor)];

      f32x16 sT = zero16();
      sT = mfma32(kc0, qf0, sT);
      sT = mfma32(kc1, qf1, sT);
      sT = mfma32(kc2, qf2, sT);
      sT = mfma32(kc3, qf3, sT);

      #pragma unroll
      for (int r = 0; r < 16; ++r) sT[r] = __builtin_amdgcn_exp2f(sT[r]);

      uint32 cw0 = cvtpk(sT[0],  sT[1]),  cw1 = cvtpk(sT[2],  sT[3]);
      uint32 cw2 = cvtpk(sT[4],  sT[5]),  cw3 = cvtpk(sT[6],  sT[7]);
      uint32 cw4 = cvtpk(sT[8],  sT[9]),  cw5 = cvtpk(sT[10], sT[11]);
      uint32 cw6 = cvtpk(sT[12], sT[13]), cw7 = cvtpk(sT[14], sT[15]);
      permswap(cw0, cw2); permswap(cw1, cw3);
      permswap(cw4, cw6); permswap(cw5, cw7);
      bf16x8 pa0 = __builtin_bit_cast(bf16x8, u32x4{cw0, cw1, cw2, cw3});
      bf16x8 pa1 = __builtin_bit_cast(bf16x8, u32x4{cw4, cw5, cw6, cw7});

      const int vr0 = l31 * 64, vr1 = (l31 + 32) * 64;
      bf16x8 v00 = *(const bf16x8*)&vt[vr0 + ((ksub + hi * 8)      ^ sxor)];
      bf16x8 v01 = *(const bf16x8*)&vt[vr0 + ((ksub + 16 + hi * 8) ^ sxor)];
      bf16x8 v10 = *(const bf16x8*)&vt[vr1 + ((ksub + hi * 8)      ^ sxor)];
      bf16x8 v11 = *(const bf16x8*)&vt[vr1 + ((ksub + 16 + hi * 8) ^ sxor)];

      rs   = mfma32(pa0, ones, rs);
      rs   = mfma32(pa1, ones, rs);
      acc0 = mfma32(pa0, v00, acc0);
      acc0 = mfma32(pa1, v01, acc0);
      acc1 = mfma32(pa0, v10, acc1);
      acc1 = mfma32(pa1, v11, acc1);
    }
    asm volatile("s_waitcnt vmcnt(0)");
    __syncthreads();
    cur ^= 1;
  }

  if (l31 == 0) {
    float* lsp = Ls + ((size_t)kh * 56 + inst) * 2048 + qbase;
    #pragma unroll
    for (int r = 0; r < 16; ++r) {
      const int qrow = (r & 3) + 8 * (r >> 2) + 4 * hi;
      lsp[qrow] = rs[r];
    }
  }
  uint32* op = Op32 + (size_t)kh * (56u * 2048u * 32u)
                    + ((size_t)inst * 2048 + qbase) * 32 + l31;
  #pragma unroll
  for (int r = 0; r < 16; ++r) {
    const int qrow = (r & 3) + 8 * (r >> 2) + 4 * hi;
    op[(size_t)qrow * 32] = cvtpk(acc0[r], acc1[r]);
  }
}

// ---------------- gather + combine split-K + normalize + LayerNorm -> xln ----------------
__global__ __launch_bounds__(256) void ln_gather(
    const uint32* __restrict__ Op32, const float* __restrict__ Ls,
    const float* __restrict__ gamma, const float* __restrict__ beta,
    u16* __restrict__ xln)
{
  const int row = blockIdx.x;            // 0..16383
  const int b = row >> 13, nn = row & 8191;
  const int tid = threadIdx.x;
  const size_t KHOFF = 56u * 2048u * 32u;
  float v[3];
  #pragma unroll
  for (int j = 0; j < 3; ++j) {
    const int e = tid + j * 256;
    const int h = e >> 6, d = e & 63;
    const int grp = h >> 2, hg = h & 3;
    const int p = nn & ((2048 << grp) - 1);
    float val = 0.f;
    if ((p & ((1 << grp) - 1)) == grp) {
      const int seg = nn >> (11 + grp);
      const int instB = (grp == 0) ? 0 : (grp == 1) ? 32 : 48;
      const int inst = instB + ((b * (4 >> grp) + seg) << 2) + hg;
      const int t = (p - grp) >> grp;
      const size_t wbase = ((size_t)inst * 2048 + t) * 32 + (d & 31);
      const uint32 w0 = Op32[wbase];
      const uint32 w1 = Op32[wbase + KHOFF];
      const float o0 = __builtin_bit_cast(float, d < 32 ? (w0 << 16) : (w0 & 0xFFFF0000u));
      const float o1 = __builtin_bit_cast(float, d < 32 ? (w1 << 16) : (w1 & 0xFFFF0000u));
      const float s = Ls[(size_t)inst * 2048 + t] + Ls[(size_t)(56 * 2048) + inst * 2048 + t];
      val = (o0 + o1) * (1.0f / (3.0f * s));
    }
    v[j] = val;
  }
  float s = v[0] + v[1] + v[2];
  float q = v[0]*v[0] + v[1]*v[1] + v[2]*v[2];
  #pragma unroll
  for (int off = 1; off < 64; off <<= 1) { s += __shfl_xor(s, off); q += __shfl_xor(q, off); }
  __shared__ float red[8];
  const int w = tid >> 6, l = tid & 63;
  if (l == 0) { red[w] = s; red[4 + w] = q; }
  __syncthreads();
  s = red[0] + red[1] + red[2] + red[3];
  q = red[4] + red[5] + red[6] + red[7];
  const float mu = s * (1.f / 768.f);
  const float var = q * (1.f / 768.f) - mu * mu;
  const float rs = rsqrtf(var + 1e-5f);
  #pragma unroll
  for (int j = 0; j < 3; ++j) {
    const int e = tid + j * 256;
    xln[(size_t)row * 768 + e] = f2bf((v[j] - mu) * rs * gamma[e] + beta[e]);
  }
}

// ---------------- output projection GEMM (bf16 A and B via swizzled global_load_lds) ----------------
__global__ __launch_bounds__(256) void out_gemm(
    const u16* __restrict__ Xb, const u16* __restrict__ W,
    const float* __restrict__ bias, float* __restrict__ out)
{
  __shared__ u16 As[2][128 * 32];
  __shared__ u16 Bs[2][128 * 32];
  const int tid = threadIdx.x;
  const int l = tid & 63, w = tid >> 6;
  const int l15 = l & 15, lh = l >> 4;
  const int wr = w >> 1, wc = w & 1;
  const int row0 = blockIdx.x * 128, col0 = blockIdx.y * 128;

  const int gr = l >> 2;
  const int gcx = ((l & 3) ^ ((gr >> 1) & 3)) * 8;   // pre-swizzled source chunk [T2]
  const u16* asrc0 = Xb + (size_t)(row0 + w * 32 + gr) * 768 + gcx;
  const u16* wsrc0 = W  + (size_t)(col0 + w * 32 + gr) * 768 + gcx;

  f32x4 acc[4][4];
  #pragma unroll
  for (int i = 0; i < 4; ++i)
    #pragma unroll
    for (int j = 0; j < 4; ++j) acc[i][j] = f32x4{0.f, 0.f, 0.f, 0.f};

  auto STAGE = [&](int buf, int ks){
    const u16* as = asrc0 + ks * 32;
    const u16* ws = wsrc0 + ks * 32;
    gload16(as,            &As[buf][(w * 32) * 32]);
    gload16(as + 16 * 768, &As[buf][(w * 32 + 16) * 32]);
    gload16(ws,            &Bs[buf][(w * 32) * 32]);
    gload16(ws + 16 * 768, &Bs[buf][(w * 32 + 16) * 32]);
  };

  STAGE(0, 0);
  asm volatile("s_waitcnt vmcnt(0)");
  __syncthreads();

  const int bxor = ((l15 >> 1) & 3) * 8;   // read-side XOR
  int cur = 0;
  for (int ks = 0; ks < 24; ++ks) {
    const int nxt = cur ^ 1;
    if (ks < 23) STAGE(nxt, ks + 1);
    bf16x8 af[4], bfr[4];
    #pragma unroll
    for (int mi = 0; mi < 4; ++mi)
      af[mi] = *(const bf16x8*)&As[cur][(wr * 64 + mi * 16 + l15) * 32 + ((lh * 8) ^ bxor)];
    #pragma unroll
    for (int ni = 0; ni < 4; ++ni)
      bfr[ni] = *(const bf16x8*)&Bs[cur][(wc * 64 + ni * 16 + l15) * 32 + ((lh * 8) ^ bxor)];
    #pragma unroll
    for (int mi = 0; mi < 4; ++mi)
      #pragma unroll
      for (int ni = 0; ni < 4; ++ni)
        acc[mi][ni] = mfma16(af[mi], bfr[ni], acc[mi][ni]);
    asm volatile("s_waitcnt vmcnt(0)");
    __syncthreads();
    cur = nxt;
  }

  #pragma unroll
  for (int ni = 0; ni < 4; ++ni) {
    const int e = col0 + wc * 64 + ni * 16 + l15;
    const float bia = bias[e];
    #pragma unroll
    for (int mi = 0; mi < 4; ++mi) {
      #pragma unroll
      for (int r = 0; r < 4; ++r) {
        const int row = row0 + wr * 64 + mi * 16 + lh * 4 + r;
        out[(size_t)row * 768 + e] = acc[mi][ni][r] + bia;
      }
    }
  }
}

extern "C" void kernel_launch(void* const* d_in, const int* in_sizes, int n_in,
                              void* d_out, int out_size, void* d_ws, size_t ws_size,
                              hipStream_t stream) {
  const float* query = (const float*)d_in[0];
  const float* key_  = (const float*)d_in[1];
  const float* value = (const float*)d_in[2];
  const float* Wq = (const float*)d_in[3];
  const float* bq = (const float*)d_in[4];
  const float* Wk = (const float*)d_in[5];
  const float* bk = (const float*)d_in[6];
  const float* Wv = (const float*)d_in[7];
  const float* bv = (const float*)d_in[8];
  const float* Wo = (const float*)d_in[9];
  const float* bo = (const float*)d_in[10];
  const float* lng = (const float*)d_in[11];
  const float* lnb = (const float*)d_in[12];

  char* ws = (char*)d_ws;
  size_t off = 0;
  auto alloc = [&](size_t bytes) { size_t o = off; off += (bytes + 255) & ~(size_t)255; return o; };
  const size_t WB = 768 * 768 * 2;           // bf16 weight bytes
  const size_t GB = (size_t)56 * ISTR * 2;   // gathered bf16 bytes
  u16* wqb = (u16*)(ws + alloc(WB));
  u16* wkb = (u16*)(ws + alloc(WB));
  u16* wvb = (u16*)(ws + alloc(WB));
  u16* wob = (u16*)(ws + alloc(WB));
  u16* Qg  = (u16*)(ws + alloc(GB));
  u16* Kg  = (u16*)(ws + alloc(GB));
  u16* VgT = (u16*)(ws + alloc(GB));
  uint32* Op32 = (uint32*)(ws + alloc((size_t)2 * 56 * 2048 * 32 * 4));
  float* Lsb  = (float*)(ws + alloc((size_t)2 * 56 * 2048 * 4));
  u16* xln = (u16*)(ws + alloc((size_t)16384 * 768 * 2));

  const int n4 = 768 * 768 / 4;
  cvt_w4<<<dim3(576, 4), 256, 0, stream>>>(Wq, Wk, Wv, Wo, wqb, wkb, wvb, wob, n4);

  qkv_fused<<<dim3(128, 18), 256, 0, stream>>>(
      query, key_, value, wqb, wkb, wvb, bq, bk, bv, Qg, Kg, VgT);

  dil_attn<<<dim3(1792), 256, 0, stream>>>(Qg, Kg, VgT, Op32, Lsb);
  ln_gather<<<dim3(16384), 256, 0, stream>>>(Op32, Lsb, lng, lnb, xln);
  out_gemm<<<dim3(128, 6), 256, 0, stream>>>(xln, wob, bo, (float*)d_out);
}